// Round 2
// baseline (276.202 us; speedup 1.0000x reference)
//
#include <hip/hip_runtime.h>
#include <hip/hip_bf16.h>

typedef __attribute__((ext_vector_type(4))) float f32x4;
typedef __attribute__((ext_vector_type(8))) short short8;
typedef unsigned short u16;

#define MFMA(a, b, c) __builtin_amdgcn_mfma_f32_16x16x32_bf16((a), (b), (c), 0, 0, 0)

static constexpr int EMBED = 768;
static constexpr int NH = 12;
static constexpr int HD = 64;
static constexpr int BATCH = 8;
static constexpr int SEQ = 1024;

__device__ __forceinline__ u16 f2bu(float f) {
    __hip_bfloat16 h = __float2bfloat16(f);
    u16 u; __builtin_memcpy(&u, &h, 2); return u;
}
__device__ __forceinline__ float exp2a(float x) {
    float r; asm("v_exp_f32 %0, %1" : "=v"(r) : "v"(x)); return r;
}

// ---------------- fp32 -> bf16 convert (vectorized) ----------------
__global__ void cvt_bf16_k(const float* __restrict__ in, u16* __restrict__ out, int n) {
    int i = (blockIdx.x * blockDim.x + threadIdx.x) * 4;
    if (i >= n) return;
    float4 v = *reinterpret_cast<const float4*>(in + i);
    ushort4 o;
    o.x = f2bu(v.x); o.y = f2bu(v.y); o.z = f2bu(v.z); o.w = f2bu(v.w);
    *reinterpret_cast<ushort4*>(out + i) = o;
}

// ---------------- bf16 B^T GEMM: C[M,N] = A[M,K] * Bw[N,K]^T + bias ----------------
template <int EPI>
__global__ __launch_bounds__(256)
void gemm_bt_k(const u16* __restrict__ A, const u16* __restrict__ Bw,
               const float* __restrict__ bias,
               u16* __restrict__ q_out, u16* __restrict__ k_out,
               u16* __restrict__ vt_out, float* __restrict__ f_out)
{
    __shared__ __attribute__((aligned(16))) char smem[32768];
    char* As = smem;
    char* Bs = smem + 16384;
    const int tid  = threadIdx.x;
    const int wave = tid >> 6, lane = tid & 63;
    const int hi   = lane >> 4, l15 = lane & 15;
    const int wr   = wave >> 1, wc = wave & 1;
    const int bm   = blockIdx.x, bn = blockIdx.y;

    f32x4 acc[4][4] = {};

    const size_t arow0 = (size_t)bm * 128;
    const size_t brow0 = (size_t)bn * 128;

    for (int kt = 0; kt < EMBED; kt += 64) {
        __syncthreads();
#pragma unroll
        for (int c = 0; c < 4; ++c) {
            int ck   = c * 4 + wave;
            int p    = ck * 1024 + lane * 16;
            int row  = p >> 7;
            int pcol = (p & 127) ^ ((row & 7) << 4);
            const u16* srcA = A  + (arow0 + row) * EMBED + kt + (pcol >> 1);
            const u16* srcB = Bw + (brow0 + row) * EMBED + kt + (pcol >> 1);
            __builtin_amdgcn_global_load_lds((const __attribute__((address_space(1))) void*)srcA,
                                             (__attribute__((address_space(3))) void*)(As + ck * 1024), 16, 0, 0);
            __builtin_amdgcn_global_load_lds((const __attribute__((address_space(1))) void*)srcB,
                                             (__attribute__((address_space(3))) void*)(Bs + ck * 1024), 16, 0, 0);
        }
        __syncthreads();
#pragma unroll
        for (int kk = 0; kk < 2; ++kk) {
            short8 af[4], bf[4];
#pragma unroll
            for (int mi = 0; mi < 4; ++mi) {
                int R  = wr * 64 + mi * 16 + l15;
                int Cb = kk * 64 + hi * 16;
                af[mi] = *reinterpret_cast<const short8*>(As + R * 128 + (Cb ^ ((R & 7) << 4)));
            }
#pragma unroll
            for (int ni = 0; ni < 4; ++ni) {
                int R  = wc * 64 + ni * 16 + l15;
                int Cb = kk * 64 + hi * 16;
                bf[ni] = *reinterpret_cast<const short8*>(Bs + R * 128 + (Cb ^ ((R & 7) << 4)));
            }
#pragma unroll
            for (int mi = 0; mi < 4; ++mi)
#pragma unroll
                for (int ni = 0; ni < 4; ++ni)
                    acc[mi][ni] = MFMA(af[mi], bf[ni], acc[mi][ni]);
        }
    }

#pragma unroll
    for (int mi = 0; mi < 4; ++mi) {
        int crow0 = bm * 128 + wr * 64 + mi * 16 + hi * 4;
#pragma unroll
        for (int ni = 0; ni < 4; ++ni) {
            int ccol = bn * 128 + wc * 64 + ni * 16 + l15;
            float bv = bias[ccol];
#pragma unroll
            for (int r = 0; r < 4; ++r) {
                float v  = acc[mi][ni][r] + bv;
                int crow = crow0 + r;
                if constexpr (EPI == 0) {
                    int which = ccol / 768;
                    int rem   = ccol - which * 768;
                    int hh = rem >> 6, hd = rem & 63;
                    int bb = crow >> 10, nn = crow & 1023;
                    size_t bh = (size_t)(bb * NH + hh);
                    // fold SCALE * log2(e) into Q so attention softmax runs in exp2 domain
                    if (which == 0)      q_out[(bh * SEQ + nn) * HD + hd] = f2bu(v * 0.18033688f);
                    else if (which == 1) k_out[(bh * SEQ + nn) * HD + hd] = f2bu(v);
                    else                 vt_out[(bh * HD + hd) * SEQ + nn] = f2bu(v);
                } else {
                    f_out[(size_t)crow * EMBED + ccol] = v;
                }
            }
        }
    }
}

// ---------------- flash attention v2: swapped QK^T, in-lane softmax ----------------
// Block = 4 waves x 16 q-rows. Lane holds S^T: q = lane&15, k = kb*16 + 4*(lane>>4) + r.
__global__ __launch_bounds__(256)
void attn_k(const u16* __restrict__ Q, const u16* __restrict__ K,
            const u16* __restrict__ Vt, u16* __restrict__ AO)
{
    __shared__ __attribute__((aligned(16))) u16 plds[4][16][72]; // 144B rows: b128 reads conflict-free
    const int tid = threadIdx.x;
    const int w   = tid >> 6, lane = tid & 63;
    const int hi  = lane >> 4, l15 = lane & 15;
    // XCD-aware mapping: 12 bh per XCD (12*256KB = 3MB fits 4MB L2); all 16 q-blocks of a bh co-XCD
    const int f   = blockIdx.x;
    const int xcd = f & 7, i = f >> 3;          // i in 0..191
    const int bh  = xcd * 12 + (i % 12);
    const int q0  = (i / 12) * 64 + w * 16;

    const u16* Qh = Q  + (size_t)bh * SEQ * HD;
    const u16* Kh = K  + (size_t)bh * SEQ * HD;
    const u16* Vh = Vt + (size_t)bh * HD * SEQ;

    short8 qf[2];  // B-operand: lane l15 = q column, contiguous d
#pragma unroll
    for (int dh = 0; dh < 2; ++dh)
        qf[dh] = *reinterpret_cast<const short8*>(Qh + (size_t)(q0 + l15) * HD + dh * 32 + hi * 8);

    f32x4 accO[4] = {};          // O: row q = 4*hi+r, col d = db*16+l15
    float m = -1e30f, l = 0.f;   // per-lane: running max/sum for q = l15 (log2 domain)

    for (int kt = 0; kt < SEQ; kt += 64) {
        // S^T tile: rows k (64), cols q (16)
        f32x4 st[4] = {};
#pragma unroll
        for (int kb = 0; kb < 4; ++kb)
#pragma unroll
            for (int dh = 0; dh < 2; ++dh) {
                short8 kf = *reinterpret_cast<const short8*>(
                    Kh + (size_t)(kt + kb * 16 + l15) * HD + dh * 32 + hi * 8);
                st[kb] = MFMA(kf, qf[dh], st[kb]);
            }
        // in-lane max over 16 values, then reduce across the 4 hi-groups
        float t0 = fmaxf(fmaxf(st[0][0], st[0][1]), fmaxf(st[0][2], st[0][3]));
        float t1 = fmaxf(fmaxf(st[1][0], st[1][1]), fmaxf(st[1][2], st[1][3]));
        float t2 = fmaxf(fmaxf(st[2][0], st[2][1]), fmaxf(st[2][2], st[2][3]));
        float t3 = fmaxf(fmaxf(st[3][0], st[3][1]), fmaxf(st[3][2], st[3][3]));
        float tm = fmaxf(fmaxf(t0, t1), fmaxf(t2, t3));
        tm = fmaxf(tm, __shfl_xor(tm, 16, 64));
        tm = fmaxf(tm, __shfl_xor(tm, 32, 64));
        float mn = fmaxf(m, tm);
        float sc = exp2a(m - mn);
        m = mn;
        // exp in place (P^T in registers)
#pragma unroll
        for (int kb = 0; kb < 4; ++kb)
#pragma unroll
            for (int r = 0; r < 4; ++r)
                st[kb][r] = exp2a(st[kb][r] - mn);
        // in-lane pairwise sum + cross-group reduce
        float s0 = (st[0][0] + st[0][1]) + (st[0][2] + st[0][3]);
        float s1 = (st[1][0] + st[1][1]) + (st[1][2] + st[1][3]);
        float s2 = (st[2][0] + st[2][1]) + (st[2][2] + st[2][3]);
        float s3 = (st[3][0] + st[3][1]) + (st[3][2] + st[3][3]);
        float ps = (s0 + s1) + (s2 + s3);
        ps += __shfl_xor(ps, 16, 64);
        ps += __shfl_xor(ps, 32, 64);
        l = l * sc + ps;
        // pack P to bf16 pairs and store transposed slots: row q=l15, k = kb*16+4*hi+{0..3}
#pragma unroll
        for (int kb = 0; kb < 4; ++kb)
#pragma unroll
            for (int j = 0; j < 2; ++j) {
                unsigned pr = (unsigned)f2bu(st[kb][2 * j]) | ((unsigned)f2bu(st[kb][2 * j + 1]) << 16);
                *reinterpret_cast<unsigned*>(&plds[w][l15][kb * 16 + hi * 4 + 2 * j]) = pr;
            }
        // rescale accO: its row q = 4*hi + r; sc for that q lives at lane l15' = 4*hi+r (any group)
        float sq0 = __shfl(sc, 4 * hi + 0, 16);
        float sq1 = __shfl(sc, 4 * hi + 1, 16);
        float sq2 = __shfl(sc, 4 * hi + 2, 16);
        float sq3 = __shfl(sc, 4 * hi + 3, 16);
#pragma unroll
        for (int db = 0; db < 4; ++db) {
            accO[db][0] *= sq0; accO[db][1] *= sq1;
            accO[db][2] *= sq2; accO[db][3] *= sq3;
        }
        // read P back as A-operand: lane l15 = q row, k = kk*32 + hi*8 + j
        short8 pa0 = *reinterpret_cast<const short8*>(&plds[w][l15][hi * 8]);
        short8 pa1 = *reinterpret_cast<const short8*>(&plds[w][l15][32 + hi * 8]);
        __builtin_amdgcn_sched_barrier(0); // keep next tile's P writes after these reads
        // O += P * V  (B-operand from V^T rows: contiguous b128)
#pragma unroll
        for (int db = 0; db < 4; ++db) {
            short8 vf0 = *reinterpret_cast<const short8*>(
                Vh + (size_t)(db * 16 + l15) * SEQ + kt + hi * 8);
            short8 vf1 = *reinterpret_cast<const short8*>(
                Vh + (size_t)(db * 16 + l15) * SEQ + kt + 32 + hi * 8);
            accO[db] = MFMA(pa0, vf0, accO[db]);
            accO[db] = MFMA(pa1, vf1, accO[db]);
        }
    }

    float linv = 1.f / l;
    float i0 = __shfl(linv, 4 * hi + 0, 16);
    float i1 = __shfl(linv, 4 * hi + 1, 16);
    float i2 = __shfl(linv, 4 * hi + 2, 16);
    float i3 = __shfl(linv, 4 * hi + 3, 16);
    float ir[4] = {i0, i1, i2, i3};
    const int bb = bh / NH, hh = bh - bb * NH;
#pragma unroll
    for (int r = 0; r < 4; ++r) {
        size_t row = (size_t)bb * SEQ + q0 + 4 * hi + r;
#pragma unroll
        for (int db = 0; db < 4; ++db)
            AO[row * EMBED + hh * HD + db * 16 + l15] = f2bu(accO[db][r] * ir[r]);
    }
}

// ---------------- launch ----------------
extern "C" void kernel_launch(void* const* d_in, const int* in_sizes, int n_in,
                              void* d_out, int out_size, void* d_ws, size_t ws_size,
                              hipStream_t stream)
{
    const float* x      = (const float*)d_in[0];
    const float* qkv_w  = (const float*)d_in[1];
    const float* qkv_b  = (const float*)d_in[2];
    const float* proj_w = (const float*)d_in[3];
    const float* proj_b = (const float*)d_in[4];
    float* out = (float*)d_out;

    char* ws = (char*)d_ws;
    u16* xb  = (u16*)(ws);
    u16* wb  = (u16*)(ws + 12582912);
    u16* pw  = (u16*)(ws + 16121856);
    u16* qb  = (u16*)(ws + 17301504);
    u16* kb  = (u16*)(ws + 29884416);
    u16* vt  = (u16*)(ws + 42467328);
    u16* ao  = (u16*)(ws + 55050240);

    cvt_bf16_k<<<6144, 256, 0, stream>>>(x,      xb, BATCH * SEQ * EMBED);
    cvt_bf16_k<<<1728, 256, 0, stream>>>(qkv_w,  wb, 3 * EMBED * EMBED);
    cvt_bf16_k<<<576,  256, 0, stream>>>(proj_w, pw, EMBED * EMBED);

    gemm_bt_k<0><<<dim3(64, 18), 256, 0, stream>>>(xb, wb, qkv_b, qb, kb, vt, nullptr);
    attn_k<<<1536, 256, 0, stream>>>(qb, kb, vt, ao);
    gemm_bt_k<1><<<dim3(64, 6), 256, 0, stream>>>(ao, pw, proj_b, nullptr, nullptr, nullptr, out);
}

// Round 3
// 270.219 us; speedup vs baseline: 1.0221x; 1.0221x over previous
//
#include <hip/hip_runtime.h>
#include <hip/hip_bf16.h>

typedef __attribute__((ext_vector_type(4))) float f32x4;
typedef __attribute__((ext_vector_type(8))) short short8;
typedef unsigned short u16;

#define MFMA(a, b, c) __builtin_amdgcn_mfma_f32_16x16x32_bf16((a), (b), (c), 0, 0, 0)

static constexpr int EMBED = 768;
static constexpr int NH = 12;
static constexpr int HD = 64;
static constexpr int BATCH = 8;
static constexpr int SEQ = 1024;

__device__ __forceinline__ u16 f2bu(float f) {
    __hip_bfloat16 h = __float2bfloat16(f);
    u16 u; __builtin_memcpy(&u, &h, 2); return u;
}
__device__ __forceinline__ float exp2a(float x) {
    float r; asm("v_exp_f32 %0, %1" : "=v"(r) : "v"(x)); return r;
}
__device__ __forceinline__ unsigned cvt_pk_bf16(float lo, float hi) {
    unsigned r; asm("v_cvt_pk_bf16_f32 %0, %1, %2" : "=v"(r) : "v"(lo), "v"(hi)); return r;
}

// ---------------- fp32 -> bf16 convert (vectorized) ----------------
__global__ void cvt_bf16_k(const float* __restrict__ in, u16* __restrict__ out, int n) {
    int i = (blockIdx.x * blockDim.x + threadIdx.x) * 4;
    if (i >= n) return;
    float4 v = *reinterpret_cast<const float4*>(in + i);
    ushort4 o;
    o.x = f2bu(v.x); o.y = f2bu(v.y); o.z = f2bu(v.z); o.w = f2bu(v.w);
    *reinterpret_cast<ushort4*>(out + i) = o;
}

// ---------------- bf16 B^T GEMM: C[M,N] = A[M,K] * Bw[N,K]^T + bias ----------------
template <int EPI>
__global__ __launch_bounds__(256)
void gemm_bt_k(const u16* __restrict__ A, const u16* __restrict__ Bw,
               const float* __restrict__ bias,
               u16* __restrict__ q_out, u16* __restrict__ k_out,
               u16* __restrict__ vt_out, float* __restrict__ f_out)
{
    __shared__ __attribute__((aligned(16))) char smem[32768];
    char* As = smem;
    char* Bs = smem + 16384;
    const int tid  = threadIdx.x;
    const int wave = tid >> 6, lane = tid & 63;
    const int hi   = lane >> 4, l15 = lane & 15;
    const int wr   = wave >> 1, wc = wave & 1;
    const int bm   = blockIdx.x, bn = blockIdx.y;

    f32x4 acc[4][4] = {};

    const size_t arow0 = (size_t)bm * 128;
    const size_t brow0 = (size_t)bn * 128;

    for (int kt = 0; kt < EMBED; kt += 64) {
        __syncthreads();
#pragma unroll
        for (int c = 0; c < 4; ++c) {
            int ck   = c * 4 + wave;
            int p    = ck * 1024 + lane * 16;
            int row  = p >> 7;
            int pcol = (p & 127) ^ ((row & 7) << 4);
            const u16* srcA = A  + (arow0 + row) * EMBED + kt + (pcol >> 1);
            const u16* srcB = Bw + (brow0 + row) * EMBED + kt + (pcol >> 1);
            __builtin_amdgcn_global_load_lds((const __attribute__((address_space(1))) void*)srcA,
                                             (__attribute__((address_space(3))) void*)(As + ck * 1024), 16, 0, 0);
            __builtin_amdgcn_global_load_lds((const __attribute__((address_space(1))) void*)srcB,
                                             (__attribute__((address_space(3))) void*)(Bs + ck * 1024), 16, 0, 0);
        }
        __syncthreads();
#pragma unroll
        for (int kk = 0; kk < 2; ++kk) {
            short8 af[4], bf[4];
#pragma unroll
            for (int mi = 0; mi < 4; ++mi) {
                int R  = wr * 64 + mi * 16 + l15;
                int Cb = kk * 64 + hi * 16;
                af[mi] = *reinterpret_cast<const short8*>(As + R * 128 + (Cb ^ ((R & 7) << 4)));
            }
#pragma unroll
            for (int ni = 0; ni < 4; ++ni) {
                int R  = wc * 64 + ni * 16 + l15;
                int Cb = kk * 64 + hi * 16;
                bf[ni] = *reinterpret_cast<const short8*>(Bs + R * 128 + (Cb ^ ((R & 7) << 4)));
            }
#pragma unroll
            for (int mi = 0; mi < 4; ++mi)
#pragma unroll
                for (int ni = 0; ni < 4; ++ni)
                    acc[mi][ni] = MFMA(af[mi], bf[ni], acc[mi][ni]);
        }
    }

#pragma unroll
    for (int mi = 0; mi < 4; ++mi) {
        int crow0 = bm * 128 + wr * 64 + mi * 16 + hi * 4;
#pragma unroll
        for (int ni = 0; ni < 4; ++ni) {
            int ccol = bn * 128 + wc * 64 + ni * 16 + l15;
            float bv = bias[ccol];
#pragma unroll
            for (int r = 0; r < 4; ++r) {
                float v  = acc[mi][ni][r] + bv;
                int crow = crow0 + r;
                if constexpr (EPI == 0) {
                    int which = ccol / 768;
                    int rem   = ccol - which * 768;
                    int hh = rem >> 6, hd = rem & 63;
                    int bb = crow >> 10, nn = crow & 1023;
                    size_t bh = (size_t)(bb * NH + hh);
                    // fold SCALE * log2(e) into Q so attention softmax runs in exp2 domain
                    if (which == 0)      q_out[(bh * SEQ + nn) * HD + hd] = f2bu(v * 0.18033688f);
                    else if (which == 1) k_out[(bh * SEQ + nn) * HD + hd] = f2bu(v);
                    else                 vt_out[(bh * HD + hd) * SEQ + nn] = f2bu(v);
                } else {
                    f_out[(size_t)crow * EMBED + ccol] = v;
                }
            }
        }
    }
}

// ---------------- flash attention v3: swapped QK^T AND swapped PV (O^T), KVBLK=128 ----------------
// Lane (l15,hi) holds S^T: q = q0 + l15, k = kb*16 + 4*hi + r.
// accO^T: col q = l15, row d = db*16 + 4*hi + r  -> sc and 1/l are per-lane scalars.
__global__ __launch_bounds__(256)
void attn_k(const u16* __restrict__ Q, const u16* __restrict__ K,
            const u16* __restrict__ Vt, u16* __restrict__ AO)
{
    __shared__ __attribute__((aligned(16))) u16 plds[4][16][136]; // 272B rows (16B-aligned)
    const int tid = threadIdx.x;
    const int w   = tid >> 6, lane = tid & 63;
    const int hi  = lane >> 4, l15 = lane & 15;
    // XCD-aware: 12 bh per XCD; all 16 q-blocks of a bh co-XCD (K/V stay in that XCD's L2)
    const int f   = blockIdx.x;
    const int xcd = f & 7, i = f >> 3;
    const int bh  = xcd * 12 + (i % 12);
    const int q0  = (i / 12) * 64 + w * 16;

    const u16* Qh = Q  + (size_t)bh * SEQ * HD;
    const u16* Kh = K  + (size_t)bh * SEQ * HD;
    const u16* Vh = Vt + (size_t)bh * HD * SEQ;

    short8 qf[2];  // B-operand: col = l15 = q, k(d) = dh*32 + hi*8 + j
#pragma unroll
    for (int dh = 0; dh < 2; ++dh)
        qf[dh] = *reinterpret_cast<const short8*>(Qh + (size_t)(q0 + l15) * HD + dh * 32 + hi * 8);

    f32x4 accO[4] = {};          // O^T: col q = l15, row d = db*16 + 4*hi + r
    float m = -1e30f, lp = 0.f;  // m uniform per l15-column; lp = per-lane partial sum

    for (int kt = 0; kt < SEQ; kt += 128) {
        // ---- QK^T (swapped): S^T[k][q], 16 MFMA, K loads burst-issued ----
        f32x4 st[8] = {};
#pragma unroll
        for (int kb = 0; kb < 8; ++kb) {
            const u16* kr = Kh + (size_t)(kt + kb * 16 + l15) * HD + hi * 8;
            short8 kf0 = *reinterpret_cast<const short8*>(kr);
            short8 kf1 = *reinterpret_cast<const short8*>(kr + 32);
            st[kb] = MFMA(kf0, qf[0], st[kb]);
            st[kb] = MFMA(kf1, qf[1], st[kb]);
        }
        // ---- V early loads (kk=0,1): latency hides under softmax ----
        short8 va[2][4];
#pragma unroll
        for (int kk = 0; kk < 2; ++kk)
#pragma unroll
            for (int db = 0; db < 4; ++db)
                va[kk][db] = *reinterpret_cast<const short8*>(
                    Vh + (size_t)(db * 16 + l15) * SEQ + kt + kk * 32 + hi * 8);
        // ---- online softmax: in-lane max tree + 2 shfls; defer-max rescale ----
        float t0 = fmaxf(fmaxf(st[0][0], st[0][1]), fmaxf(st[0][2], st[0][3]));
        float t1 = fmaxf(fmaxf(st[1][0], st[1][1]), fmaxf(st[1][2], st[1][3]));
        float t2 = fmaxf(fmaxf(st[2][0], st[2][1]), fmaxf(st[2][2], st[2][3]));
        float t3 = fmaxf(fmaxf(st[3][0], st[3][1]), fmaxf(st[3][2], st[3][3]));
        float t4 = fmaxf(fmaxf(st[4][0], st[4][1]), fmaxf(st[4][2], st[4][3]));
        float t5 = fmaxf(fmaxf(st[5][0], st[5][1]), fmaxf(st[5][2], st[5][3]));
        float t6 = fmaxf(fmaxf(st[6][0], st[6][1]), fmaxf(st[6][2], st[6][3]));
        float t7 = fmaxf(fmaxf(st[7][0], st[7][1]), fmaxf(st[7][2], st[7][3]));
        float tm = fmaxf(fmaxf(fmaxf(t0, t1), fmaxf(t2, t3)),
                         fmaxf(fmaxf(t4, t5), fmaxf(t6, t7)));
        tm = fmaxf(tm, __shfl_xor(tm, 16, 64));
        tm = fmaxf(tm, __shfl_xor(tm, 32, 64));
        if (!__all(tm <= m + 8.f)) {   // rare: rescale (per-lane, no broadcasts)
            float mn = fmaxf(m, tm);
            float sc = exp2a(m - mn);
            m = mn;
            lp *= sc;
#pragma unroll
            for (int db = 0; db < 4; ++db)
#pragma unroll
                for (int r = 0; r < 4; ++r) accO[db][r] *= sc;
        }
        // ---- exp2, per-lane partial sum, pack to LDS (P rows: q=l15, cols k) ----
#pragma unroll
        for (int kb = 0; kb < 8; ++kb) {
            float e0 = exp2a(st[kb][0] - m);
            float e1 = exp2a(st[kb][1] - m);
            float e2 = exp2a(st[kb][2] - m);
            float e3 = exp2a(st[kb][3] - m);
            lp += (e0 + e1) + (e2 + e3);
            unsigned* dst = reinterpret_cast<unsigned*>(&plds[w][l15][kb * 16 + hi * 4]);
            dst[0] = cvt_pk_bf16(e0, e1);
            dst[1] = cvt_pk_bf16(e2, e3);
        }
        // ---- P back as B-operand (col q=l15, k rows = kk*32+hi*8+j) ----
        short8 pa[4];
#pragma unroll
        for (int kk = 0; kk < 4; ++kk)
            pa[kk] = *reinterpret_cast<const short8*>(&plds[w][l15][kk * 32 + hi * 8]);
        // ---- V late loads (kk=2,3) ----
        short8 vb[2][4];
#pragma unroll
        for (int kk = 0; kk < 2; ++kk)
#pragma unroll
            for (int db = 0; db < 4; ++db)
                vb[kk][db] = *reinterpret_cast<const short8*>(
                    Vh + (size_t)(db * 16 + l15) * SEQ + kt + (kk + 2) * 32 + hi * 8);
        __builtin_amdgcn_sched_barrier(0); // pin: next tile's P writes stay below these reads
        // ---- O^T += V^T * P : A = V^T frag (row d, k cols), B = P frag ----
#pragma unroll
        for (int db = 0; db < 4; ++db) {
            accO[db] = MFMA(va[0][db], pa[0], accO[db]);
            accO[db] = MFMA(va[1][db], pa[1], accO[db]);
            accO[db] = MFMA(vb[0][db], pa[2], accO[db]);
            accO[db] = MFMA(vb[1][db], pa[3], accO[db]);
        }
    }

    // final l: sum per-lane partials across hi-groups (2 shfls, once)
    lp += __shfl_xor(lp, 16, 64);
    lp += __shfl_xor(lp, 32, 64);
    float linv = 1.f / lp;   // uniform per l15-column = per q
    const int bb = bh / NH, hh = bh - bb * NH;
    float* aorow_base = nullptr; (void)aorow_base;
    size_t rowb = ((size_t)bb * SEQ + q0 + l15) * EMBED + hh * HD;
#pragma unroll
    for (int db = 0; db < 4; ++db) {
        float o0 = accO[db][0] * linv, o1 = accO[db][1] * linv;
        float o2 = accO[db][2] * linv, o3 = accO[db][3] * linv;
        uint2 pkd;
        pkd.x = cvt_pk_bf16(o0, o1);
        pkd.y = cvt_pk_bf16(o2, o3);
        *reinterpret_cast<uint2*>(&AO[rowb + db * 16 + hi * 4]) = pkd;
    }
}

// ---------------- launch ----------------
extern "C" void kernel_launch(void* const* d_in, const int* in_sizes, int n_in,
                              void* d_out, int out_size, void* d_ws, size_t ws_size,
                              hipStream_t stream)
{
    const float* x      = (const float*)d_in[0];
    const float* qkv_w  = (const float*)d_in[1];
    const float* qkv_b  = (const float*)d_in[2];
    const float* proj_w = (const float*)d_in[3];
    const float* proj_b = (const float*)d_in[4];
    float* out = (float*)d_out;

    char* ws = (char*)d_ws;
    u16* xb  = (u16*)(ws);
    u16* wb  = (u16*)(ws + 12582912);
    u16* pw  = (u16*)(ws + 16121856);
    u16* qb  = (u16*)(ws + 17301504);
    u16* kb  = (u16*)(ws + 29884416);
    u16* vt  = (u16*)(ws + 42467328);
    u16* ao  = (u16*)(ws + 55050240);

    cvt_bf16_k<<<6144, 256, 0, stream>>>(x,      xb, BATCH * SEQ * EMBED);
    cvt_bf16_k<<<1728, 256, 0, stream>>>(qkv_w,  wb, 3 * EMBED * EMBED);
    cvt_bf16_k<<<576,  256, 0, stream>>>(proj_w, pw, EMBED * EMBED);

    gemm_bt_k<0><<<dim3(64, 18), 256, 0, stream>>>(xb, wb, qkv_b, qb, kb, vt, nullptr);
    attn_k<<<1536, 256, 0, stream>>>(qb, kb, vt, ao);
    gemm_bt_k<1><<<dim3(64, 6), 256, 0, stream>>>(ao, pw, proj_b, nullptr, nullptr, nullptr, out);
}

// Round 4
// 145.509 us; speedup vs baseline: 1.8982x; 1.8571x over previous
//
#include <hip/hip_runtime.h>
#include <hip/hip_bf16.h>

typedef __attribute__((ext_vector_type(4))) float f32x4;
typedef __attribute__((ext_vector_type(8))) short short8;
typedef unsigned short u16;

#define MFMA(a, b, c) __builtin_amdgcn_mfma_f32_16x16x32_bf16((a), (b), (c), 0, 0, 0)

static constexpr int EMBED = 768;
static constexpr int NH = 12;
static constexpr int HD = 64;
static constexpr int BATCH = 8;
static constexpr int SEQ = 1024;

__device__ __forceinline__ u16 f2bu(float f) {
    __hip_bfloat16 h = __float2bfloat16(f);
    u16 u; __builtin_memcpy(&u, &h, 2); return u;
}
__device__ __forceinline__ float exp2a(float x) {
    float r; asm("v_exp_f32 %0, %1" : "=v"(r) : "v"(x)); return r;
}
__device__ __forceinline__ unsigned cvt_pk_bf16(float lo, float hi) {
    unsigned r; asm("v_cvt_pk_bf16_f32 %0, %1, %2" : "=v"(r) : "v"(lo), "v"(hi)); return r;
}

// ---------------- fp32 -> bf16 convert (vectorized) ----------------
__global__ void cvt_bf16_k(const float* __restrict__ in, u16* __restrict__ out, int n) {
    int i = (blockIdx.x * blockDim.x + threadIdx.x) * 4;
    if (i >= n) return;
    float4 v = *reinterpret_cast<const float4*>(in + i);
    ushort4 o;
    o.x = f2bu(v.x); o.y = f2bu(v.y); o.z = f2bu(v.z); o.w = f2bu(v.w);
    *reinterpret_cast<ushort4*>(out + i) = o;
}

// ---------------- bf16 B^T GEMM: C[M,N] = A[M,K] * Bw[N,K]^T + bias ----------------
template <int EPI>
__global__ __launch_bounds__(256)
void gemm_bt_k(const u16* __restrict__ A, const u16* __restrict__ Bw,
               const float* __restrict__ bias,
               u16* __restrict__ q_out, u16* __restrict__ k_out,
               u16* __restrict__ vt_out, float* __restrict__ f_out)
{
    __shared__ __attribute__((aligned(16))) char smem[32768];
    char* As = smem;
    char* Bs = smem + 16384;
    const int tid  = threadIdx.x;
    const int wave = tid >> 6, lane = tid & 63;
    const int hi   = lane >> 4, l15 = lane & 15;
    const int wr   = wave >> 1, wc = wave & 1;
    const int bm   = blockIdx.x, bn = blockIdx.y;

    f32x4 acc[4][4] = {};

    const size_t arow0 = (size_t)bm * 128;
    const size_t brow0 = (size_t)bn * 128;

    for (int kt = 0; kt < EMBED; kt += 64) {
        __syncthreads();
#pragma unroll
        for (int c = 0; c < 4; ++c) {
            int ck   = c * 4 + wave;
            int p    = ck * 1024 + lane * 16;
            int row  = p >> 7;
            int pcol = (p & 127) ^ ((row & 7) << 4);
            const u16* srcA = A  + (arow0 + row) * EMBED + kt + (pcol >> 1);
            const u16* srcB = Bw + (brow0 + row) * EMBED + kt + (pcol >> 1);
            __builtin_amdgcn_global_load_lds((const __attribute__((address_space(1))) void*)srcA,
                                             (__attribute__((address_space(3))) void*)(As + ck * 1024), 16, 0, 0);
            __builtin_amdgcn_global_load_lds((const __attribute__((address_space(1))) void*)srcB,
                                             (__attribute__((address_space(3))) void*)(Bs + ck * 1024), 16, 0, 0);
        }
        __syncthreads();
#pragma unroll
        for (int kk = 0; kk < 2; ++kk) {
            short8 af[4], bf[4];
#pragma unroll
            for (int mi = 0; mi < 4; ++mi) {
                int R  = wr * 64 + mi * 16 + l15;
                int Cb = kk * 64 + hi * 16;
                af[mi] = *reinterpret_cast<const short8*>(As + R * 128 + (Cb ^ ((R & 7) << 4)));
            }
#pragma unroll
            for (int ni = 0; ni < 4; ++ni) {
                int R  = wc * 64 + ni * 16 + l15;
                int Cb = kk * 64 + hi * 16;
                bf[ni] = *reinterpret_cast<const short8*>(Bs + R * 128 + (Cb ^ ((R & 7) << 4)));
            }
#pragma unroll
            for (int mi = 0; mi < 4; ++mi)
#pragma unroll
                for (int ni = 0; ni < 4; ++ni)
                    acc[mi][ni] = MFMA(af[mi], bf[ni], acc[mi][ni]);
        }
    }

#pragma unroll
    for (int mi = 0; mi < 4; ++mi) {
        int crow0 = bm * 128 + wr * 64 + mi * 16 + hi * 4;
#pragma unroll
        for (int ni = 0; ni < 4; ++ni) {
            int ccol = bn * 128 + wc * 64 + ni * 16 + l15;
            float bv = bias[ccol];
#pragma unroll
            for (int r = 0; r < 4; ++r) {
                float v  = acc[mi][ni][r] + bv;
                int crow = crow0 + r;
                if constexpr (EPI == 0) {
                    int which = ccol / 768;
                    int rem   = ccol - which * 768;
                    int hh = rem >> 6, hd = rem & 63;
                    int bb = crow >> 10, nn = crow & 1023;
                    size_t bh = (size_t)(bb * NH + hh);
                    // fold SCALE * log2(e) into Q so attention softmax runs in exp2 domain
                    if (which == 0)      q_out[(bh * SEQ + nn) * HD + hd] = f2bu(v * 0.18033688f);
                    else if (which == 1) k_out[(bh * SEQ + nn) * HD + hd] = f2bu(v);
                    else                 vt_out[(bh * HD + hd) * SEQ + nn] = f2bu(v);
                } else {
                    f_out[(size_t)crow * EMBED + ccol] = v;
                }
            }
        }
    }
}

// ---------------- flash attention v4: LDS-staged K/V, 4 waves x 32 q-rows, KVBLK=64 ----------------
// Swapped QK^T (S^T) + swapped PV (O^T). Lane (l15,hi): q = qh*16 + l15, k = kb*16 + 4*hi + r.
__global__ __launch_bounds__(256)
void attn_k(const u16* __restrict__ Q, const u16* __restrict__ K,
            const u16* __restrict__ Vt, u16* __restrict__ AO)
{
    __shared__ __attribute__((aligned(16))) u16 kls[2][4096];   // K tile: 64 k-rows x 64 d (swizzled)
    __shared__ __attribute__((aligned(16))) u16 vls[2][4096];   // V^T tile: 64 d-rows x 64 k (swizzled)
    __shared__ __attribute__((aligned(16))) u16 plds[4][32][72];// per-wave P^T roundtrip, padded rows

    const int tid = threadIdx.x;
    const int w   = tid >> 6, lane = tid & 63;
    const int hi  = lane >> 4, l15 = lane & 15;
    // XCD-aware: 12 bh per XCD; all 8 q-blocks of a bh co-XCD
    const int f   = blockIdx.x;
    const int xcd = f & 7, i = f >> 3;           // i in 0..95
    const int bh  = xcd * 12 + (i % 12);
    const int q0w = (i / 12) * 128 + w * 32;     // this wave's 32 q-rows

    const u16* Qh = Q  + (size_t)bh * SEQ * HD;
    const u16* Kh = K  + (size_t)bh * SEQ * HD;
    const u16* Vh = Vt + (size_t)bh * HD * SEQ;

    // Q fragments (B-operand): qf[qh][dh], col = l15, k(d) = dh*32 + hi*8 + j
    short8 qf[2][2];
#pragma unroll
    for (int qh = 0; qh < 2; ++qh)
#pragma unroll
        for (int dh = 0; dh < 2; ++dh)
            qf[qh][dh] = *reinterpret_cast<const short8*>(
                Qh + (size_t)(q0w + qh * 16 + l15) * HD + dh * 32 + hi * 8);

    // stage one 64-k tile: K (8 KB) + V^T (8 KB) = 16 chunks of 1 KB; each wave 4 chunks
    auto stage = [&](int buf, int kt) {
#pragma unroll
        for (int c = 0; c < 4; ++c) {
            int ch   = c * 4 + w;        // 0..15
            int mc   = ch & 7;
            int p    = mc * 1024 + lane * 16;
            int row  = p >> 7;                       // 0..63
            int colb = (p & 127) ^ ((row & 7) << 4); // pre-swizzled source col (bytes)
            const u16* src;
            u16* dst;
            if (ch < 8) { src = Kh + (size_t)(kt + row) * HD + (colb >> 1); dst = kls[buf] + mc * 512; }
            else        { src = Vh + (size_t)row * SEQ + kt + (colb >> 1);  dst = vls[buf] + mc * 512; }
            __builtin_amdgcn_global_load_lds((const __attribute__((address_space(1))) void*)src,
                                             (__attribute__((address_space(3))) void*)dst, 16, 0, 0);
        }
    };

    f32x4 accO[4][2] = {};            // O^T: [db][qh], row d = db*16+4*hi+r, col q = l15
    float m0 = -1e30f, m1 = -1e30f, lp0 = 0.f, lp1 = 0.f;

    stage(0, 0);
    int cur = 0;
    for (int t = 0; t < 16; ++t) {
        __syncthreads();                       // staging of cur complete & visible
        if (t < 15) stage(cur ^ 1, (t + 1) * 64);  // prefetch next tile (flies during compute)

        const u16* Kb = kls[cur];
        const u16* Vb = vls[cur];

        // ---- QK^T from LDS: S^T[k][q] ----
        f32x4 st[4][2] = {};
#pragma unroll
        for (int kb = 0; kb < 4; ++kb) {
            int R  = kb * 16 + l15;
            int sw = (R & 7) << 4;
            short8 kf0 = *reinterpret_cast<const short8*>(Kb + R * 64 + (((hi * 16) ^ sw) >> 1));
            short8 kf1 = *reinterpret_cast<const short8*>(Kb + R * 64 + (((64 + hi * 16) ^ sw) >> 1));
            st[kb][0] = MFMA(kf0, qf[0][0], st[kb][0]);
            st[kb][0] = MFMA(kf1, qf[0][1], st[kb][0]);
            st[kb][1] = MFMA(kf0, qf[1][0], st[kb][1]);
            st[kb][1] = MFMA(kf1, qf[1][1], st[kb][1]);
        }

        // ---- online softmax (per qh), defer-max ----
        float a0 = fmaxf(fmaxf(st[0][0][0], st[0][0][1]), fmaxf(st[0][0][2], st[0][0][3]));
        float a1 = fmaxf(fmaxf(st[1][0][0], st[1][0][1]), fmaxf(st[1][0][2], st[1][0][3]));
        float a2 = fmaxf(fmaxf(st[2][0][0], st[2][0][1]), fmaxf(st[2][0][2], st[2][0][3]));
        float a3 = fmaxf(fmaxf(st[3][0][0], st[3][0][1]), fmaxf(st[3][0][2], st[3][0][3]));
        float tm0 = fmaxf(fmaxf(a0, a1), fmaxf(a2, a3));
        float b0 = fmaxf(fmaxf(st[0][1][0], st[0][1][1]), fmaxf(st[0][1][2], st[0][1][3]));
        float b1 = fmaxf(fmaxf(st[1][1][0], st[1][1][1]), fmaxf(st[1][1][2], st[1][1][3]));
        float b2 = fmaxf(fmaxf(st[2][1][0], st[2][1][1]), fmaxf(st[2][1][2], st[2][1][3]));
        float b3 = fmaxf(fmaxf(st[3][1][0], st[3][1][1]), fmaxf(st[3][1][2], st[3][1][3]));
        float tm1 = fmaxf(fmaxf(b0, b1), fmaxf(b2, b3));
        tm0 = fmaxf(tm0, __shfl_xor(tm0, 16, 64));
        tm0 = fmaxf(tm0, __shfl_xor(tm0, 32, 64));
        tm1 = fmaxf(tm1, __shfl_xor(tm1, 16, 64));
        tm1 = fmaxf(tm1, __shfl_xor(tm1, 32, 64));
        if (!__all((tm0 <= m0 + 8.f) && (tm1 <= m1 + 8.f))) {
            float mn0 = fmaxf(m0, tm0), mn1 = fmaxf(m1, tm1);
            float sc0 = exp2a(m0 - mn0), sc1 = exp2a(m1 - mn1);
            m0 = mn0; m1 = mn1;
            lp0 *= sc0; lp1 *= sc1;
#pragma unroll
            for (int db = 0; db < 4; ++db)
#pragma unroll
                for (int r = 0; r < 4; ++r) {
                    accO[db][0][r] *= sc0;
                    accO[db][1][r] *= sc1;
                }
        }

        // ---- exp2, partial sums, pack P^T to LDS ----
#pragma unroll
        for (int kb = 0; kb < 4; ++kb) {
            float e0 = exp2a(st[kb][0][0] - m0);
            float e1 = exp2a(st[kb][0][1] - m0);
            float e2 = exp2a(st[kb][0][2] - m0);
            float e3 = exp2a(st[kb][0][3] - m0);
            lp0 += (e0 + e1) + (e2 + e3);
            unsigned* d0 = reinterpret_cast<unsigned*>(&plds[w][l15][kb * 16 + hi * 4]);
            d0[0] = cvt_pk_bf16(e0, e1);
            d0[1] = cvt_pk_bf16(e2, e3);
            float g0 = exp2a(st[kb][1][0] - m1);
            float g1 = exp2a(st[kb][1][1] - m1);
            float g2 = exp2a(st[kb][1][2] - m1);
            float g3 = exp2a(st[kb][1][3] - m1);
            lp1 += (g0 + g1) + (g2 + g3);
            unsigned* d1 = reinterpret_cast<unsigned*>(&plds[w][16 + l15][kb * 16 + hi * 4]);
            d1[0] = cvt_pk_bf16(g0, g1);
            d1[1] = cvt_pk_bf16(g2, g3);
        }

        // ---- P back as B-operand: pa[qh][kk], col q = l15, k = kk*32 + hi*8 + j ----
        short8 pa[2][2];
#pragma unroll
        for (int qh = 0; qh < 2; ++qh)
#pragma unroll
            for (int kk = 0; kk < 2; ++kk)
                pa[qh][kk] = *reinterpret_cast<const short8*>(&plds[w][qh * 16 + l15][kk * 32 + hi * 8]);

        // ---- O^T += V^T * P from LDS ----
#pragma unroll
        for (int db = 0; db < 4; ++db) {
            int R  = db * 16 + l15;
            int sw = (R & 7) << 4;
            short8 vf0 = *reinterpret_cast<const short8*>(Vb + R * 64 + (((hi * 16) ^ sw) >> 1));
            short8 vf1 = *reinterpret_cast<const short8*>(Vb + R * 64 + (((64 + hi * 16) ^ sw) >> 1));
            accO[db][0] = MFMA(vf0, pa[0][0], accO[db][0]);
            accO[db][0] = MFMA(vf1, pa[0][1], accO[db][0]);
            accO[db][1] = MFMA(vf0, pa[1][0], accO[db][1]);
            accO[db][1] = MFMA(vf1, pa[1][1], accO[db][1]);
        }

        cur ^= 1;
        __syncthreads();                       // all reads of old cur done -> safe to overwrite
    }

    // final l reduction (once) and store O^T -> AO rows
    lp0 += __shfl_xor(lp0, 16, 64);
    lp0 += __shfl_xor(lp0, 32, 64);
    lp1 += __shfl_xor(lp1, 16, 64);
    lp1 += __shfl_xor(lp1, 32, 64);
    float linv0 = 1.f / lp0, linv1 = 1.f / lp1;
    const int bb = bh / NH, hh = bh - bb * NH;
#pragma unroll
    for (int qh = 0; qh < 2; ++qh) {
        float linv = qh ? linv1 : linv0;
        size_t rowb = ((size_t)bb * SEQ + q0w + qh * 16 + l15) * EMBED + hh * HD;
#pragma unroll
        for (int db = 0; db < 4; ++db) {
            float o0 = accO[db][qh][0] * linv, o1 = accO[db][qh][1] * linv;
            float o2 = accO[db][qh][2] * linv, o3 = accO[db][qh][3] * linv;
            uint2 pkd;
            pkd.x = cvt_pk_bf16(o0, o1);
            pkd.y = cvt_pk_bf16(o2, o3);
            *reinterpret_cast<uint2*>(&AO[rowb + db * 16 + hi * 4]) = pkd;
        }
    }
}

// ---------------- launch ----------------
extern "C" void kernel_launch(void* const* d_in, const int* in_sizes, int n_in,
                              void* d_out, int out_size, void* d_ws, size_t ws_size,
                              hipStream_t stream)
{
    const float* x      = (const float*)d_in[0];
    const float* qkv_w  = (const float*)d_in[1];
    const float* qkv_b  = (const float*)d_in[2];
    const float* proj_w = (const float*)d_in[3];
    const float* proj_b = (const float*)d_in[4];
    float* out = (float*)d_out;

    char* ws = (char*)d_ws;
    u16* xb  = (u16*)(ws);
    u16* wb  = (u16*)(ws + 12582912);
    u16* pw  = (u16*)(ws + 16121856);
    u16* qb  = (u16*)(ws + 17301504);
    u16* kb  = (u16*)(ws + 29884416);
    u16* vt  = (u16*)(ws + 42467328);
    u16* ao  = (u16*)(ws + 55050240);

    cvt_bf16_k<<<6144, 256, 0, stream>>>(x,      xb, BATCH * SEQ * EMBED);
    cvt_bf16_k<<<1728, 256, 0, stream>>>(qkv_w,  wb, 3 * EMBED * EMBED);
    cvt_bf16_k<<<576,  256, 0, stream>>>(proj_w, pw, EMBED * EMBED);

    gemm_bt_k<0><<<dim3(64, 18), 256, 0, stream>>>(xb, wb, qkv_b, qb, kb, vt, nullptr);
    attn_k<<<768, 256, 0, stream>>>(qb, kb, vt, ao);
    gemm_bt_k<1><<<dim3(64, 6), 256, 0, stream>>>(ao, pw, proj_b, nullptr, nullptr, nullptr, out);
}

// Round 5
// 119.675 us; speedup vs baseline: 2.3079x; 1.2159x over previous
//
#include <hip/hip_runtime.h>
#include <hip/hip_bf16.h>

typedef __attribute__((ext_vector_type(4))) float f32x4;
typedef __attribute__((ext_vector_type(8))) short short8;
typedef unsigned short u16;

#define MFMA(a, b, c) __builtin_amdgcn_mfma_f32_16x16x32_bf16((a), (b), (c), 0, 0, 0)

static constexpr int EMBED = 768;
static constexpr int NH = 12;
static constexpr int HD = 64;
static constexpr int BATCH = 8;
static constexpr int SEQ = 1024;

__device__ __forceinline__ u16 f2bu(float f) {
    __hip_bfloat16 h = __float2bfloat16(f);
    u16 u; __builtin_memcpy(&u, &h, 2); return u;
}
__device__ __forceinline__ float exp2a(float x) {
    float r; asm("v_exp_f32 %0, %1" : "=v"(r) : "v"(x)); return r;
}
__device__ __forceinline__ unsigned cvt_pk_bf16(float lo, float hi) {
    unsigned r; asm("v_cvt_pk_bf16_f32 %0, %1, %2" : "=v"(r) : "v"(lo), "v"(hi)); return r;
}

// ---------------- fp32 -> bf16 convert (vectorized) ----------------
__global__ void cvt_bf16_k(const float* __restrict__ in, u16* __restrict__ out, int n) {
    int i = (blockIdx.x * blockDim.x + threadIdx.x) * 4;
    if (i >= n) return;
    float4 v = *reinterpret_cast<const float4*>(in + i);
    ushort4 o;
    o.x = f2bu(v.x); o.y = f2bu(v.y); o.z = f2bu(v.z); o.w = f2bu(v.w);
    *reinterpret_cast<ushort4*>(out + i) = o;
}

// ---------------- bf16 B^T GEMM: C[M,N] = A[M,K] * Bw[N,K]^T + bias ----------------
// 128x128 tile, BK=64, 4 waves. DOUBLE-BUFFERED LDS with prefetch-before-compute:
// stage(t+1) issued at top, compute(t), bottom barrier drains -> latency hidden.
template <int EPI>
__global__ __launch_bounds__(256)
void gemm_bt_k(const u16* __restrict__ A, const u16* __restrict__ Bw,
               const float* __restrict__ bias,
               u16* __restrict__ q_out, u16* __restrict__ k_out,
               u16* __restrict__ vt_out, float* __restrict__ f_out)
{
    __shared__ __attribute__((aligned(16))) char smem[65536]; // 2 x (A 16KB + B 16KB)
    const int tid  = threadIdx.x;
    const int wave = tid >> 6, lane = tid & 63;
    const int hi   = lane >> 4, l15 = lane & 15;
    const int wr   = wave >> 1, wc = wave & 1;
    const int bm   = blockIdx.x, bn = blockIdx.y;

    f32x4 acc[4][4] = {};

    const size_t arow0 = (size_t)bm * 128;
    const size_t brow0 = (size_t)bn * 128;

    auto stage = [&](int buf, int kt) {
        char* Ab = smem + buf * 32768;
        char* Bb = Ab + 16384;
#pragma unroll
        for (int c = 0; c < 4; ++c) {
            int ck   = c * 4 + wave;
            int p    = ck * 1024 + lane * 16;
            int row  = p >> 7;
            int pcol = (p & 127) ^ ((row & 7) << 4);
            const u16* srcA = A  + (arow0 + row) * EMBED + kt + (pcol >> 1);
            const u16* srcB = Bw + (brow0 + row) * EMBED + kt + (pcol >> 1);
            __builtin_amdgcn_global_load_lds((const __attribute__((address_space(1))) void*)srcA,
                                             (__attribute__((address_space(3))) void*)(Ab + ck * 1024), 16, 0, 0);
            __builtin_amdgcn_global_load_lds((const __attribute__((address_space(1))) void*)srcB,
                                             (__attribute__((address_space(3))) void*)(Bb + ck * 1024), 16, 0, 0);
        }
    };

    stage(0, 0);
    int cur = 0;
    for (int t = 0; t < 12; ++t) {
        __syncthreads();                         // stage(cur) drained (prev bottom barrier) & visible
        if (t < 11) stage(cur ^ 1, (t + 1) * 64); // prefetch next: flies during compute below
        const char* Ab = smem + cur * 32768;
        const char* Bb = Ab + 16384;
#pragma unroll
        for (int kk = 0; kk < 2; ++kk) {
            short8 af[4], bf[4];
#pragma unroll
            for (int mi = 0; mi < 4; ++mi) {
                int R  = wr * 64 + mi * 16 + l15;
                int Cb = kk * 64 + hi * 16;
                af[mi] = *reinterpret_cast<const short8*>(Ab + R * 128 + (Cb ^ ((R & 7) << 4)));
            }
#pragma unroll
            for (int ni = 0; ni < 4; ++ni) {
                int R  = wc * 64 + ni * 16 + l15;
                int Cb = kk * 64 + hi * 16;
                bf[ni] = *reinterpret_cast<const short8*>(Bb + R * 128 + (Cb ^ ((R & 7) << 4)));
            }
#pragma unroll
            for (int mi = 0; mi < 4; ++mi)
#pragma unroll
                for (int ni = 0; ni < 4; ++ni)
                    acc[mi][ni] = MFMA(af[mi], bf[ni], acc[mi][ni]);
        }
        cur ^= 1;
        __syncthreads();                         // reads of old cur done; drain of prefetch happens here
    }

    // epilogue: C/D layout col = lane&15, row = 4*(lane>>4)+reg
#pragma unroll
    for (int mi = 0; mi < 4; ++mi) {
        int crow0 = bm * 128 + wr * 64 + mi * 16 + hi * 4;
#pragma unroll
        for (int ni = 0; ni < 4; ++ni) {
            int ccol = bn * 128 + wc * 64 + ni * 16 + l15;
            float bv = bias[ccol];
            if constexpr (EPI == 0) {
                int which = ccol / 768;          // uniform across the 16-col strip
                int rem   = ccol - which * 768;
                int hh = rem >> 6, hd = rem & 63;
                int bb = crow0 >> 10, nn0 = crow0 & 1023;   // uniform for r=0..3
                size_t bh = (size_t)(bb * NH + hh);
                if (which == 2) {
                    // V^T: r=0..3 are consecutive nn -> pack one dwordx2 store
                    uint2 pk;
                    pk.x = cvt_pk_bf16(acc[mi][ni][0] + bv, acc[mi][ni][1] + bv);
                    pk.y = cvt_pk_bf16(acc[mi][ni][2] + bv, acc[mi][ni][3] + bv);
                    *reinterpret_cast<uint2*>(&vt_out[(bh * HD + hd) * SEQ + nn0]) = pk;
                } else if (which == 0) {
#pragma unroll
                    for (int r = 0; r < 4; ++r)
                        q_out[(bh * SEQ + nn0 + r) * HD + hd] =
                            f2bu((acc[mi][ni][r] + bv) * 0.18033688f); // SCALE*log2e folded
                } else {
#pragma unroll
                    for (int r = 0; r < 4; ++r)
                        k_out[(bh * SEQ + nn0 + r) * HD + hd] = f2bu(acc[mi][ni][r] + bv);
                }
            } else {
#pragma unroll
                for (int r = 0; r < 4; ++r)
                    f_out[(size_t)(crow0 + r) * EMBED + ccol] = acc[mi][ni][r] + bv;
            }
        }
    }
}

// ---------------- flash attention v4: LDS-staged K/V, 4 waves x 32 q-rows, KVBLK=64 ----------------
// Swapped QK^T (S^T) + swapped PV (O^T). Lane (l15,hi): q = qh*16 + l15, k = kb*16 + 4*hi + r.
__global__ __launch_bounds__(256)
void attn_k(const u16* __restrict__ Q, const u16* __restrict__ K,
            const u16* __restrict__ Vt, u16* __restrict__ AO)
{
    __shared__ __attribute__((aligned(16))) u16 kls[2][4096];   // K tile: 64 k-rows x 64 d (swizzled)
    __shared__ __attribute__((aligned(16))) u16 vls[2][4096];   // V^T tile: 64 d-rows x 64 k (swizzled)
    __shared__ __attribute__((aligned(16))) u16 plds[4][32][72];// per-wave P^T roundtrip, padded rows

    const int tid = threadIdx.x;
    const int w   = tid >> 6, lane = tid & 63;
    const int hi  = lane >> 4, l15 = lane & 15;
    const int f   = blockIdx.x;
    const int xcd = f & 7, i = f >> 3;
    const int bh  = xcd * 12 + (i % 12);
    const int q0w = (i / 12) * 128 + w * 32;

    const u16* Qh = Q  + (size_t)bh * SEQ * HD;
    const u16* Kh = K  + (size_t)bh * SEQ * HD;
    const u16* Vh = Vt + (size_t)bh * HD * SEQ;

    short8 qf[2][2];
#pragma unroll
    for (int qh = 0; qh < 2; ++qh)
#pragma unroll
        for (int dh = 0; dh < 2; ++dh)
            qf[qh][dh] = *reinterpret_cast<const short8*>(
                Qh + (size_t)(q0w + qh * 16 + l15) * HD + dh * 32 + hi * 8);

    auto stage = [&](int buf, int kt) {
#pragma unroll
        for (int c = 0; c < 4; ++c) {
            int ch   = c * 4 + w;
            int mc   = ch & 7;
            int p    = mc * 1024 + lane * 16;
            int row  = p >> 7;
            int colb = (p & 127) ^ ((row & 7) << 4);
            const u16* src;
            u16* dst;
            if (ch < 8) { src = Kh + (size_t)(kt + row) * HD + (colb >> 1); dst = kls[buf] + mc * 512; }
            else        { src = Vh + (size_t)row * SEQ + kt + (colb >> 1);  dst = vls[buf] + mc * 512; }
            __builtin_amdgcn_global_load_lds((const __attribute__((address_space(1))) void*)src,
                                             (__attribute__((address_space(3))) void*)dst, 16, 0, 0);
        }
    };

    f32x4 accO[4][2] = {};
    float m0 = -1e30f, m1 = -1e30f, lp0 = 0.f, lp1 = 0.f;

    stage(0, 0);
    int cur = 0;
    for (int t = 0; t < 16; ++t) {
        __syncthreads();
        if (t < 15) stage(cur ^ 1, (t + 1) * 64);

        const u16* Kb = kls[cur];
        const u16* Vb = vls[cur];

        f32x4 st[4][2] = {};
#pragma unroll
        for (int kb = 0; kb < 4; ++kb) {
            int R  = kb * 16 + l15;
            int sw = (R & 7) << 4;
            short8 kf0 = *reinterpret_cast<const short8*>(Kb + R * 64 + (((hi * 16) ^ sw) >> 1));
            short8 kf1 = *reinterpret_cast<const short8*>(Kb + R * 64 + (((64 + hi * 16) ^ sw) >> 1));
            st[kb][0] = MFMA(kf0, qf[0][0], st[kb][0]);
            st[kb][0] = MFMA(kf1, qf[0][1], st[kb][0]);
            st[kb][1] = MFMA(kf0, qf[1][0], st[kb][1]);
            st[kb][1] = MFMA(kf1, qf[1][1], st[kb][1]);
        }

        float a0 = fmaxf(fmaxf(st[0][0][0], st[0][0][1]), fmaxf(st[0][0][2], st[0][0][3]));
        float a1 = fmaxf(fmaxf(st[1][0][0], st[1][0][1]), fmaxf(st[1][0][2], st[1][0][3]));
        float a2 = fmaxf(fmaxf(st[2][0][0], st[2][0][1]), fmaxf(st[2][0][2], st[2][0][3]));
        float a3 = fmaxf(fmaxf(st[3][0][0], st[3][0][1]), fmaxf(st[3][0][2], st[3][0][3]));
        float tm0 = fmaxf(fmaxf(a0, a1), fmaxf(a2, a3));
        float b0 = fmaxf(fmaxf(st[0][1][0], st[0][1][1]), fmaxf(st[0][1][2], st[0][1][3]));
        float b1 = fmaxf(fmaxf(st[1][1][0], st[1][1][1]), fmaxf(st[1][1][2], st[1][1][3]));
        float b2 = fmaxf(fmaxf(st[2][1][0], st[2][1][1]), fmaxf(st[2][1][2], st[2][1][3]));
        float b3 = fmaxf(fmaxf(st[3][1][0], st[3][1][1]), fmaxf(st[3][1][2], st[3][1][3]));
        float tm1 = fmaxf(fmaxf(b0, b1), fmaxf(b2, b3));
        tm0 = fmaxf(tm0, __shfl_xor(tm0, 16, 64));
        tm0 = fmaxf(tm0, __shfl_xor(tm0, 32, 64));
        tm1 = fmaxf(tm1, __shfl_xor(tm1, 16, 64));
        tm1 = fmaxf(tm1, __shfl_xor(tm1, 32, 64));
        if (!__all((tm0 <= m0 + 8.f) && (tm1 <= m1 + 8.f))) {
            float mn0 = fmaxf(m0, tm0), mn1 = fmaxf(m1, tm1);
            float sc0 = exp2a(m0 - mn0), sc1 = exp2a(m1 - mn1);
            m0 = mn0; m1 = mn1;
            lp0 *= sc0; lp1 *= sc1;
#pragma unroll
            for (int db = 0; db < 4; ++db)
#pragma unroll
                for (int r = 0; r < 4; ++r) {
                    accO[db][0][r] *= sc0;
                    accO[db][1][r] *= sc1;
                }
        }

#pragma unroll
        for (int kb = 0; kb < 4; ++kb) {
            float e0 = exp2a(st[kb][0][0] - m0);
            float e1 = exp2a(st[kb][0][1] - m0);
            float e2 = exp2a(st[kb][0][2] - m0);
            float e3 = exp2a(st[kb][0][3] - m0);
            lp0 += (e0 + e1) + (e2 + e3);
            unsigned* d0 = reinterpret_cast<unsigned*>(&plds[w][l15][kb * 16 + hi * 4]);
            d0[0] = cvt_pk_bf16(e0, e1);
            d0[1] = cvt_pk_bf16(e2, e3);
            float g0 = exp2a(st[kb][1][0] - m1);
            float g1 = exp2a(st[kb][1][1] - m1);
            float g2 = exp2a(st[kb][1][2] - m1);
            float g3 = exp2a(st[kb][1][3] - m1);
            lp1 += (g0 + g1) + (g2 + g3);
            unsigned* d1 = reinterpret_cast<unsigned*>(&plds[w][16 + l15][kb * 16 + hi * 4]);
            d1[0] = cvt_pk_bf16(g0, g1);
            d1[1] = cvt_pk_bf16(g2, g3);
        }

        short8 pa[2][2];
#pragma unroll
        for (int qh = 0; qh < 2; ++qh)
#pragma unroll
            for (int kk = 0; kk < 2; ++kk)
                pa[qh][kk] = *reinterpret_cast<const short8*>(&plds[w][qh * 16 + l15][kk * 32 + hi * 8]);

#pragma unroll
        for (int db = 0; db < 4; ++db) {
            int R  = db * 16 + l15;
            int sw = (R & 7) << 4;
            short8 vf0 = *reinterpret_cast<const short8*>(Vb + R * 64 + (((hi * 16) ^ sw) >> 1));
            short8 vf1 = *reinterpret_cast<const short8*>(Vb + R * 64 + (((64 + hi * 16) ^ sw) >> 1));
            accO[db][0] = MFMA(vf0, pa[0][0], accO[db][0]);
            accO[db][0] = MFMA(vf1, pa[0][1], accO[db][0]);
            accO[db][1] = MFMA(vf0, pa[1][0], accO[db][1]);
            accO[db][1] = MFMA(vf1, pa[1][1], accO[db][1]);
        }

        cur ^= 1;
        __syncthreads();
    }

    lp0 += __shfl_xor(lp0, 16, 64);
    lp0 += __shfl_xor(lp0, 32, 64);
    lp1 += __shfl_xor(lp1, 16, 64);
    lp1 += __shfl_xor(lp1, 32, 64);
    float linv0 = 1.f / lp0, linv1 = 1.f / lp1;
    const int bb = bh / NH, hh = bh - bb * NH;
#pragma unroll
    for (int qh = 0; qh < 2; ++qh) {
        float linv = qh ? linv1 : linv0;
        size_t rowb = ((size_t)bb * SEQ + q0w + qh * 16 + l15) * EMBED + hh * HD;
#pragma unroll
        for (int db = 0; db < 4; ++db) {
            float o0 = accO[db][qh][0] * linv, o1 = accO[db][qh][1] * linv;
            float o2 = accO[db][qh][2] * linv, o3 = accO[db][qh][3] * linv;
            uint2 pkd;
            pkd.x = cvt_pk_bf16(o0, o1);
            pkd.y = cvt_pk_bf16(o2, o3);
            *reinterpret_cast<uint2*>(&AO[rowb + db * 16 + hi * 4]) = pkd;
        }
    }
}

// ---------------- launch ----------------
extern "C" void kernel_launch(void* const* d_in, const int* in_sizes, int n_in,
                              void* d_out, int out_size, void* d_ws, size_t ws_size,
                              hipStream_t stream)
{
    const float* x      = (const float*)d_in[0];
    const float* qkv_w  = (const float*)d_in[1];
    const float* qkv_b  = (const float*)d_in[2];
    const float* proj_w = (const float*)d_in[3];
    const float* proj_b = (const float*)d_in[4];
    float* out = (float*)d_out;

    char* ws = (char*)d_ws;
    u16* xb  = (u16*)(ws);
    u16* wb  = (u16*)(ws + 12582912);
    u16* pw  = (u16*)(ws + 16121856);
    u16* qb  = (u16*)(ws + 17301504);
    u16* kb  = (u16*)(ws + 29884416);
    u16* vt  = (u16*)(ws + 42467328);
    u16* ao  = (u16*)(ws + 55050240);

    cvt_bf16_k<<<6144, 256, 0, stream>>>(x,      xb, BATCH * SEQ * EMBED);
    cvt_bf16_k<<<1728, 256, 0, stream>>>(qkv_w,  wb, 3 * EMBED * EMBED);
    cvt_bf16_k<<<576,  256, 0, stream>>>(proj_w, pw, EMBED * EMBED);

    gemm_bt_k<0><<<dim3(64, 18), 256, 0, stream>>>(xb, wb, qkv_b, qb, kb, vt, nullptr);
    attn_k<<<768, 256, 0, stream>>>(qb, kb, vt, ao);
    gemm_bt_k<1><<<dim3(64, 6), 256, 0, stream>>>(ao, pw, proj_b, nullptr, nullptr, nullptr, out);
}

// Round 6
// 113.978 us; speedup vs baseline: 2.4233x; 1.0500x over previous
//
#include <hip/hip_runtime.h>
#include <hip/hip_bf16.h>

typedef __attribute__((ext_vector_type(4))) float f32x4;
typedef __attribute__((ext_vector_type(8))) short short8;
typedef unsigned short u16;

#define MFMA(a, b, c) __builtin_amdgcn_mfma_f32_16x16x32_bf16((a), (b), (c), 0, 0, 0)

// counted-vmcnt barrier: stage(t) landed (mine), then all waves' landed.
#define WAITVM_BAR(N) do {                                          \
    asm volatile("s_waitcnt vmcnt(" #N ")" ::: "memory");           \
    __builtin_amdgcn_s_barrier();                                   \
    __builtin_amdgcn_sched_barrier(0);                              \
} while (0)
// read-completion barrier (no drain): protects buffer about to be re-staged.
#define BAR2() do {                                                 \
    __builtin_amdgcn_sched_barrier(0);                              \
    __builtin_amdgcn_s_barrier();                                   \
    __builtin_amdgcn_sched_barrier(0);                              \
} while (0)

static constexpr int EMBED = 768;
static constexpr int NH = 12;
static constexpr int HD = 64;
static constexpr int BATCH = 8;
static constexpr int SEQ = 1024;

__device__ __forceinline__ u16 f2bu(float f) {
    __hip_bfloat16 h = __float2bfloat16(f);
    u16 u; __builtin_memcpy(&u, &h, 2); return u;
}
__device__ __forceinline__ float exp2a(float x) {
    float r; asm("v_exp_f32 %0, %1" : "=v"(r) : "v"(x)); return r;
}
__device__ __forceinline__ unsigned cvt_pk_bf16(float lo, float hi) {
    unsigned r; asm("v_cvt_pk_bf16_f32 %0, %1, %2" : "=v"(r) : "v"(lo), "v"(hi)); return r;
}
__device__ __forceinline__ float max3f(float a, float b, float c) {
    return fmaxf(fmaxf(a, b), c);   // fuses to v_max3_f32
}

// ---------------- fp32 -> bf16 convert (vectorized) ----------------
__global__ void cvt_bf16_k(const float* __restrict__ in, u16* __restrict__ out, int n) {
    int i = (blockIdx.x * blockDim.x + threadIdx.x) * 4;
    if (i >= n) return;
    float4 v = *reinterpret_cast<const float4*>(in + i);
    ushort4 o;
    o.x = f2bu(v.x); o.y = f2bu(v.y); o.z = f2bu(v.z); o.w = f2bu(v.w);
    *reinterpret_cast<ushort4*>(out + i) = o;
}

// ---------------- bf16 B^T GEMM: C[M,N] = A[M,K] * Bw[N,K]^T + bias ----------------
// 128x128 tile, BK=64, 4 waves, double-buffered LDS, raw barriers + counted vmcnt(8).
template <int EPI>
__global__ __launch_bounds__(256)
void gemm_bt_k(const u16* __restrict__ A, const u16* __restrict__ Bw,
               const float* __restrict__ bias,
               u16* __restrict__ q_out, u16* __restrict__ k_out,
               u16* __restrict__ vt_out, float* __restrict__ f_out)
{
    __shared__ __attribute__((aligned(16))) char smem[65536]; // 2 x (A 16KB + B 16KB)
    const int tid  = threadIdx.x;
    const int wave = tid >> 6, lane = tid & 63;
    const int hi   = lane >> 4, l15 = lane & 15;
    const int wr   = wave >> 1, wc = wave & 1;
    const int bm   = blockIdx.x, bn = blockIdx.y;

    f32x4 acc[4][4] = {};

    const size_t arow0 = (size_t)bm * 128;
    const size_t brow0 = (size_t)bn * 128;

    auto stage = [&](int buf, int kt) {   // 8 gll per wave
        char* Ab = smem + buf * 32768;
        char* Bb = Ab + 16384;
#pragma unroll
        for (int c = 0; c < 4; ++c) {
            int ck   = c * 4 + wave;
            int p    = ck * 1024 + lane * 16;
            int row  = p >> 7;
            int pcol = (p & 127) ^ ((row & 7) << 4);
            const u16* srcA = A  + (arow0 + row) * EMBED + kt + (pcol >> 1);
            const u16* srcB = Bw + (brow0 + row) * EMBED + kt + (pcol >> 1);
            __builtin_amdgcn_global_load_lds((const __attribute__((address_space(1))) void*)srcA,
                                             (__attribute__((address_space(3))) void*)(Ab + ck * 1024), 16, 0, 0);
            __builtin_amdgcn_global_load_lds((const __attribute__((address_space(1))) void*)srcB,
                                             (__attribute__((address_space(3))) void*)(Bb + ck * 1024), 16, 0, 0);
        }
    };

    auto comp = [&](const char* Ab, const char* Bb) {
#pragma unroll
        for (int kk = 0; kk < 2; ++kk) {
            short8 af[4], bf[4];
#pragma unroll
            for (int mi = 0; mi < 4; ++mi) {
                int R  = wr * 64 + mi * 16 + l15;
                int Cb = kk * 64 + hi * 16;
                af[mi] = *reinterpret_cast<const short8*>(Ab + R * 128 + (Cb ^ ((R & 7) << 4)));
            }
#pragma unroll
            for (int ni = 0; ni < 4; ++ni) {
                int R  = wc * 64 + ni * 16 + l15;
                int Cb = kk * 64 + hi * 16;
                bf[ni] = *reinterpret_cast<const short8*>(Bb + R * 128 + (Cb ^ ((R & 7) << 4)));
            }
#pragma unroll
            for (int mi = 0; mi < 4; ++mi)
#pragma unroll
                for (int ni = 0; ni < 4; ++ni)
                    acc[mi][ni] = MFMA(af[mi], bf[ni], acc[mi][ni]);
        }
    };

    const char* A0 = smem;
    const char* B0 = smem + 16384;
    const char* A1 = smem + 32768;
    const char* B1 = smem + 49152;

    stage(0, 0);                                   // S(0)
    // tiles 0..9 (stage always), then 10 (stage 11), then 11 (drain)
#pragma unroll
    for (int tt = 0; tt < 5; ++tt) {
        stage(1, (2 * tt + 1) * 64);               // S(2tt+1) -> buf1
        WAITVM_BAR(8);                             // S(2tt) landed everywhere
        comp(A0, B0);                              // tile 2tt
        BAR2();
        stage(0, (2 * tt + 2) * 64);               // S(2tt+2) -> buf0
        WAITVM_BAR(8);
        comp(A1, B1);                              // tile 2tt+1
        BAR2();
    }
    stage(1, 11 * 64);                             // S(11)
    WAITVM_BAR(8);                                 // S(10) landed
    comp(A0, B0);                                  // tile 10
    BAR2();
    WAITVM_BAR(0);                                 // S(11) landed
    comp(A1, B1);                                  // tile 11

    // epilogue: C/D layout col = lane&15, row = 4*(lane>>4)+reg
#pragma unroll
    for (int mi = 0; mi < 4; ++mi) {
        int crow0 = bm * 128 + wr * 64 + mi * 16 + hi * 4;
#pragma unroll
        for (int ni = 0; ni < 4; ++ni) {
            int ccol = bn * 128 + wc * 64 + ni * 16 + l15;
            float bv = bias[ccol];
            if constexpr (EPI == 0) {
                int which = ccol / 768;
                int rem   = ccol - which * 768;
                int hh = rem >> 6, hd = rem & 63;
                int bb = crow0 >> 10, nn0 = crow0 & 1023;
                size_t bh = (size_t)(bb * NH + hh);
                if (which == 2) {
                    uint2 pk;
                    pk.x = cvt_pk_bf16(acc[mi][ni][0] + bv, acc[mi][ni][1] + bv);
                    pk.y = cvt_pk_bf16(acc[mi][ni][2] + bv, acc[mi][ni][3] + bv);
                    *reinterpret_cast<uint2*>(&vt_out[(bh * HD + hd) * SEQ + nn0]) = pk;
                } else if (which == 0) {
#pragma unroll
                    for (int r = 0; r < 4; ++r)
                        q_out[(bh * SEQ + nn0 + r) * HD + hd] =
                            f2bu((acc[mi][ni][r] + bv) * 0.18033688f); // SCALE*log2e folded
                } else {
#pragma unroll
                    for (int r = 0; r < 4; ++r)
                        k_out[(bh * SEQ + nn0 + r) * HD + hd] = f2bu(acc[mi][ni][r] + bv);
                }
            } else {
#pragma unroll
                for (int r = 0; r < 4; ++r)
                    f_out[(size_t)(crow0 + r) * EMBED + ccol] = acc[mi][ni][r] + bv;
            }
        }
    }
}

// ---------------- flash attention v5: LDS K/V, raw barriers + counted vmcnt(4) ----------------
// Swapped QK^T (S^T) + swapped PV (O^T). Lane (l15,hi): q = qh*16 + l15, k = kb*16 + 4*hi + r.
__global__ __launch_bounds__(256)
void attn_k(const u16* __restrict__ Q, const u16* __restrict__ K,
            const u16* __restrict__ Vt, u16* __restrict__ AO)
{
    __shared__ __attribute__((aligned(16))) u16 kls[2][4096];
    __shared__ __attribute__((aligned(16))) u16 vls[2][4096];
    __shared__ __attribute__((aligned(16))) u16 plds[4][32][72];

    const int tid = threadIdx.x;
    const int w   = tid >> 6, lane = tid & 63;
    const int hi  = lane >> 4, l15 = lane & 15;
    const int f   = blockIdx.x;
    const int xcd = f & 7, i = f >> 3;
    const int bh  = xcd * 12 + (i % 12);
    const int q0w = (i / 12) * 128 + w * 32;

    const u16* Qh = Q  + (size_t)bh * SEQ * HD;
    const u16* Kh = K  + (size_t)bh * SEQ * HD;
    const u16* Vh = Vt + (size_t)bh * HD * SEQ;

    auto stage = [&](int buf, int kt) {   // 4 gll per wave
#pragma unroll
        for (int c = 0; c < 4; ++c) {
            int ch   = c * 4 + w;
            int mc   = ch & 7;
            int p    = mc * 1024 + lane * 16;
            int row  = p >> 7;
            int colb = (p & 127) ^ ((row & 7) << 4);
            const u16* src;
            u16* dst;
            if (ch < 8) { src = Kh + (size_t)(kt + row) * HD + (colb >> 1); dst = kls[buf] + mc * 512; }
            else        { src = Vh + (size_t)row * SEQ + kt + (colb >> 1);  dst = vls[buf] + mc * 512; }
            __builtin_amdgcn_global_load_lds((const __attribute__((address_space(1))) void*)src,
                                             (__attribute__((address_space(3))) void*)dst, 16, 0, 0);
        }
    };

    stage(0, 0);                                   // S(0) first: earliest in flight

    short8 qf[2][2];
#pragma unroll
    for (int qh = 0; qh < 2; ++qh)
#pragma unroll
        for (int dh = 0; dh < 2; ++dh)
            qf[qh][dh] = *reinterpret_cast<const short8*>(
                Qh + (size_t)(q0w + qh * 16 + l15) * HD + dh * 32 + hi * 8);

    f32x4 accO[4][2] = {};
    float m0 = -1e30f, m1 = -1e30f, lp0 = 0.f, lp1 = 0.f;

    auto tile = [&](const u16* Kb, const u16* Vb) {
        f32x4 st[4][2] = {};
#pragma unroll
        for (int kb = 0; kb < 4; ++kb) {
            int R  = kb * 16 + l15;
            int sw = (R & 7) << 4;
            short8 kf0 = *reinterpret_cast<const short8*>(Kb + R * 64 + (((hi * 16) ^ sw) >> 1));
            short8 kf1 = *reinterpret_cast<const short8*>(Kb + R * 64 + (((64 + hi * 16) ^ sw) >> 1));
            st[kb][0] = MFMA(kf0, qf[0][0], st[kb][0]);
            st[kb][0] = MFMA(kf1, qf[0][1], st[kb][0]);
            st[kb][1] = MFMA(kf0, qf[1][0], st[kb][1]);
            st[kb][1] = MFMA(kf1, qf[1][1], st[kb][1]);
        }

        // max over 16 values per qh via v_max3 trees
        float p0 = max3f(st[0][0][0], st[0][0][1], st[0][0][2]);
        float p1 = max3f(st[0][0][3], st[1][0][0], st[1][0][1]);
        float p2 = max3f(st[1][0][2], st[1][0][3], st[2][0][0]);
        float p3 = max3f(st[2][0][1], st[2][0][2], st[2][0][3]);
        float p4 = max3f(st[3][0][0], st[3][0][1], st[3][0][2]);
        float tm0 = max3f(max3f(p0, p1, p2), max3f(p3, p4, st[3][0][3]), -1e30f);
        float r0 = max3f(st[0][1][0], st[0][1][1], st[0][1][2]);
        float r1 = max3f(st[0][1][3], st[1][1][0], st[1][1][1]);
        float r2 = max3f(st[1][1][2], st[1][1][3], st[2][1][0]);
        float r3 = max3f(st[2][1][1], st[2][1][2], st[2][1][3]);
        float r4 = max3f(st[3][1][0], st[3][1][1], st[3][1][2]);
        float tm1 = max3f(max3f(r0, r1, r2), max3f(r3, r4, st[3][1][3]), -1e30f);
        tm0 = fmaxf(tm0, __shfl_xor(tm0, 16, 64));
        tm0 = fmaxf(tm0, __shfl_xor(tm0, 32, 64));
        tm1 = fmaxf(tm1, __shfl_xor(tm1, 16, 64));
        tm1 = fmaxf(tm1, __shfl_xor(tm1, 32, 64));
        if (!__all((tm0 <= m0 + 8.f) && (tm1 <= m1 + 8.f))) {
            float mn0 = fmaxf(m0, tm0), mn1 = fmaxf(m1, tm1);
            float sc0 = exp2a(m0 - mn0), sc1 = exp2a(m1 - mn1);
            m0 = mn0; m1 = mn1;
            lp0 *= sc0; lp1 *= sc1;
#pragma unroll
            for (int db = 0; db < 4; ++db)
#pragma unroll
                for (int r = 0; r < 4; ++r) {
                    accO[db][0][r] *= sc0;
                    accO[db][1][r] *= sc1;
                }
        }

#pragma unroll
        for (int kb = 0; kb < 4; ++kb) {
            float e0 = exp2a(st[kb][0][0] - m0);
            float e1 = exp2a(st[kb][0][1] - m0);
            float e2 = exp2a(st[kb][0][2] - m0);
            float e3 = exp2a(st[kb][0][3] - m0);
            lp0 += (e0 + e1) + (e2 + e3);
            unsigned* d0 = reinterpret_cast<unsigned*>(&plds[w][l15][kb * 16 + hi * 4]);
            d0[0] = cvt_pk_bf16(e0, e1);
            d0[1] = cvt_pk_bf16(e2, e3);
            float g0 = exp2a(st[kb][1][0] - m1);
            float g1 = exp2a(st[kb][1][1] - m1);
            float g2 = exp2a(st[kb][1][2] - m1);
            float g3 = exp2a(st[kb][1][3] - m1);
            lp1 += (g0 + g1) + (g2 + g3);
            unsigned* d1 = reinterpret_cast<unsigned*>(&plds[w][16 + l15][kb * 16 + hi * 4]);
            d1[0] = cvt_pk_bf16(g0, g1);
            d1[1] = cvt_pk_bf16(g2, g3);
        }

        short8 pa[2][2];
#pragma unroll
        for (int qh = 0; qh < 2; ++qh)
#pragma unroll
            for (int kk = 0; kk < 2; ++kk)
                pa[qh][kk] = *reinterpret_cast<const short8*>(&plds[w][qh * 16 + l15][kk * 32 + hi * 8]);
        __builtin_amdgcn_sched_barrier(0);  // keep P reads above next tile's writes

#pragma unroll
        for (int db = 0; db < 4; ++db) {
            int R  = db * 16 + l15;
            int sw = (R & 7) << 4;
            short8 vf0 = *reinterpret_cast<const short8*>(Vb + R * 64 + (((hi * 16) ^ sw) >> 1));
            short8 vf1 = *reinterpret_cast<const short8*>(Vb + R * 64 + (((64 + hi * 16) ^ sw) >> 1));
            accO[db][0] = MFMA(vf0, pa[0][0], accO[db][0]);
            accO[db][0] = MFMA(vf1, pa[0][1], accO[db][0]);
            accO[db][1] = MFMA(vf0, pa[1][0], accO[db][1]);
            accO[db][1] = MFMA(vf1, pa[1][1], accO[db][1]);
        }
    };

    // tiles 0..13 (always stage next), 14 (stage 15), 15 (drain)
    for (int tt = 0; tt < 7; ++tt) {
        stage(1, (2 * tt + 1) * 64);
        WAITVM_BAR(4);
        tile(kls[0], vls[0]);
        BAR2();
        stage(0, (2 * tt + 2) * 64);
        WAITVM_BAR(4);
        tile(kls[1], vls[1]);
        BAR2();
    }
    stage(1, 15 * 64);
    WAITVM_BAR(4);
    tile(kls[0], vls[0]);
    BAR2();
    WAITVM_BAR(0);
    tile(kls[1], vls[1]);

    lp0 += __shfl_xor(lp0, 16, 64);
    lp0 += __shfl_xor(lp0, 32, 64);
    lp1 += __shfl_xor(lp1, 16, 64);
    lp1 += __shfl_xor(lp1, 32, 64);
    float linv0 = 1.f / lp0, linv1 = 1.f / lp1;
    const int bb = bh / NH, hh = bh - bb * NH;
#pragma unroll
    for (int qh = 0; qh < 2; ++qh) {
        float linv = qh ? linv1 : linv0;
        size_t rowb = ((size_t)bb * SEQ + q0w + qh * 16 + l15) * EMBED + hh * HD;
#pragma unroll
        for (int db = 0; db < 4; ++db) {
            float o0 = accO[db][qh][0] * linv, o1 = accO[db][qh][1] * linv;
            float o2 = accO[db][qh][2] * linv, o3 = accO[db][qh][3] * linv;
            uint2 pkd;
            pkd.x = cvt_pk_bf16(o0, o1);
            pkd.y = cvt_pk_bf16(o2, o3);
            *reinterpret_cast<uint2*>(&AO[rowb + db * 16 + hi * 4]) = pkd;
        }
    }
}

// ---------------- launch ----------------
extern "C" void kernel_launch(void* const* d_in, const int* in_sizes, int n_in,
                              void* d_out, int out_size, void* d_ws, size_t ws_size,
                              hipStream_t stream)
{
    const float* x      = (const float*)d_in[0];
    const float* qkv_w  = (const float*)d_in[1];
    const float* qkv_b  = (const float*)d_in[2];
    const float* proj_w = (const float*)d_in[3];
    const float* proj_b = (const float*)d_in[4];
    float* out = (float*)d_out;

    char* ws = (char*)d_ws;
    u16* xb  = (u16*)(ws);
    u16* wb  = (u16*)(ws + 12582912);
    u16* pw  = (u16*)(ws + 16121856);
    u16* qb  = (u16*)(ws + 17301504);
    u16* kb  = (u16*)(ws + 29884416);
    u16* vt  = (u16*)(ws + 42467328);
    u16* ao  = (u16*)(ws + 55050240);

    cvt_bf16_k<<<6144, 256, 0, stream>>>(x,      xb, BATCH * SEQ * EMBED);
    cvt_bf16_k<<<1728, 256, 0, stream>>>(qkv_w,  wb, 3 * EMBED * EMBED);
    cvt_bf16_k<<<576,  256, 0, stream>>>(proj_w, pw, EMBED * EMBED);

    gemm_bt_k<0><<<dim3(64, 18), 256, 0, stream>>>(xb, wb, qkv_b, qb, kb, vt, nullptr);
    attn_k<<<768, 256, 0, stream>>>(qb, kb, vt, ao);
    gemm_bt_k<1><<<dim3(64, 6), 256, 0, stream>>>(ao, pw, proj_b, nullptr, nullptr, nullptr, out);
}

// Round 7
// 107.069 us; speedup vs baseline: 2.5797x; 1.0645x over previous
//
#include <hip/hip_runtime.h>
#include <hip/hip_bf16.h>

typedef __attribute__((ext_vector_type(4))) float f32x4;
typedef __attribute__((ext_vector_type(8))) short short8;
typedef unsigned short u16;

#define MFMA(a, b, c) __builtin_amdgcn_mfma_f32_16x16x32_bf16((a), (b), (c), 0, 0, 0)

// counted-vmcnt barrier: my stage(t) landed, then all waves' landed.
#define WAITVM_BAR(N) do {                                          \
    asm volatile("s_waitcnt vmcnt(" #N ")" ::: "memory");           \
    __builtin_amdgcn_s_barrier();                                   \
    __builtin_amdgcn_sched_barrier(0);                              \
} while (0)
// read-completion barrier (no drain): protects buffer about to be re-staged.
#define BAR2() do {                                                 \
    __builtin_amdgcn_sched_barrier(0);                              \
    __builtin_amdgcn_s_barrier();                                   \
    __builtin_amdgcn_sched_barrier(0);                              \
} while (0)

static constexpr int EMBED = 768;
static constexpr int NH = 12;
static constexpr int HD = 64;
static constexpr int BATCH = 8;
static constexpr int SEQ = 1024;

__device__ __forceinline__ u16 f2bu(float f) {
    __hip_bfloat16 h = __float2bfloat16(f);
    u16 u; __builtin_memcpy(&u, &h, 2); return u;
}
__device__ __forceinline__ float exp2a(float x) {
    float r; asm("v_exp_f32 %0, %1" : "=v"(r) : "v"(x)); return r;
}
__device__ __forceinline__ unsigned cvt_pk_bf16(float lo, float hi) {
    unsigned r; asm("v_cvt_pk_bf16_f32 %0, %1, %2" : "=v"(r) : "v"(lo), "v"(hi)); return r;
}
__device__ __forceinline__ float max3f(float a, float b, float c) {
    return fmaxf(fmaxf(a, b), c);   // fuses to v_max3_f32
}
// a' = {a[0:31], b[0:31]}, b' = {a[32:63], b[32:63]}
__device__ __forceinline__ void swap32(unsigned& a, unsigned& b) {
    asm volatile("v_permlane32_swap_b32 %0, %1" : "+v"(a), "+v"(b));
}
// quarters: a' = [a0,b0,a2,b2], b' = [a1,b1,a3,b3]
__device__ __forceinline__ void swap16(unsigned& a, unsigned& b) {
    asm volatile("v_permlane16_swap_b32 %0, %1" : "+v"(a), "+v"(b));
}
__device__ __forceinline__ short8 mk8(unsigned w0, unsigned w1, unsigned w2, unsigned w3) {
    union { unsigned u[4]; short8 s; } c;
    c.u[0] = w0; c.u[1] = w1; c.u[2] = w2; c.u[3] = w3;
    return c.s;
}

// ---------------- fp32 -> bf16 convert (vectorized) ----------------
__global__ void cvt_bf16_k(const float* __restrict__ in, u16* __restrict__ out, int n) {
    int i = (blockIdx.x * blockDim.x + threadIdx.x) * 4;
    if (i >= n) return;
    float4 v = *reinterpret_cast<const float4*>(in + i);
    ushort4 o;
    o.x = f2bu(v.x); o.y = f2bu(v.y); o.z = f2bu(v.z); o.w = f2bu(v.w);
    *reinterpret_cast<ushort4*>(out + i) = o;
}

// ---------------- bf16 B^T GEMM: C[M,N] = A[M,K] * Bw[N,K]^T + bias ----------------
// 128x128 tile, BK=64, 4 waves, double-buffered LDS, raw barriers + counted vmcnt(8).
template <int EPI>
__global__ __launch_bounds__(256)
void gemm_bt_k(const u16* __restrict__ A, const u16* __restrict__ Bw,
               const float* __restrict__ bias,
               u16* __restrict__ q_out, u16* __restrict__ k_out,
               u16* __restrict__ vt_out, float* __restrict__ f_out)
{
    __shared__ __attribute__((aligned(16))) char smem[65536]; // 2 x (A 16KB + B 16KB)
    const int tid  = threadIdx.x;
    const int wave = tid >> 6, lane = tid & 63;
    const int hi   = lane >> 4, l15 = lane & 15;
    const int wr   = wave >> 1, wc = wave & 1;
    const int bm   = blockIdx.x, bn = blockIdx.y;

    f32x4 acc[4][4] = {};

    const size_t arow0 = (size_t)bm * 128;
    const size_t brow0 = (size_t)bn * 128;

    auto stage = [&](int buf, int kt) {   // 8 gll per wave
        char* Ab = smem + buf * 32768;
        char* Bb = Ab + 16384;
#pragma unroll
        for (int c = 0; c < 4; ++c) {
            int ck   = c * 4 + wave;
            int p    = ck * 1024 + lane * 16;
            int row  = p >> 7;
            int pcol = (p & 127) ^ ((row & 7) << 4);
            const u16* srcA = A  + (arow0 + row) * EMBED + kt + (pcol >> 1);
            const u16* srcB = Bw + (brow0 + row) * EMBED + kt + (pcol >> 1);
            __builtin_amdgcn_global_load_lds((const __attribute__((address_space(1))) void*)srcA,
                                             (__attribute__((address_space(3))) void*)(Ab + ck * 1024), 16, 0, 0);
            __builtin_amdgcn_global_load_lds((const __attribute__((address_space(1))) void*)srcB,
                                             (__attribute__((address_space(3))) void*)(Bb + ck * 1024), 16, 0, 0);
        }
    };

    auto comp = [&](const char* Ab, const char* Bb) {
#pragma unroll
        for (int kk = 0; kk < 2; ++kk) {
            short8 af[4], bf[4];
#pragma unroll
            for (int mi = 0; mi < 4; ++mi) {
                int R  = wr * 64 + mi * 16 + l15;
                int Cb = kk * 64 + hi * 16;
                af[mi] = *reinterpret_cast<const short8*>(Ab + R * 128 + (Cb ^ ((R & 7) << 4)));
            }
#pragma unroll
            for (int ni = 0; ni < 4; ++ni) {
                int R  = wc * 64 + ni * 16 + l15;
                int Cb = kk * 64 + hi * 16;
                bf[ni] = *reinterpret_cast<const short8*>(Bb + R * 128 + (Cb ^ ((R & 7) << 4)));
            }
#pragma unroll
            for (int mi = 0; mi < 4; ++mi)
#pragma unroll
                for (int ni = 0; ni < 4; ++ni)
                    acc[mi][ni] = MFMA(af[mi], bf[ni], acc[mi][ni]);
        }
    };

    const char* A0 = smem;
    const char* B0 = smem + 16384;
    const char* A1 = smem + 32768;
    const char* B1 = smem + 49152;

    stage(0, 0);
#pragma unroll
    for (int tt = 0; tt < 5; ++tt) {
        stage(1, (2 * tt + 1) * 64);
        WAITVM_BAR(8);
        comp(A0, B0);
        BAR2();
        stage(0, (2 * tt + 2) * 64);
        WAITVM_BAR(8);
        comp(A1, B1);
        BAR2();
    }
    stage(1, 11 * 64);
    WAITVM_BAR(8);
    comp(A0, B0);
    BAR2();
    WAITVM_BAR(0);
    comp(A1, B1);

    // epilogue: C/D layout col = lane&15, row = 4*(lane>>4)+reg
#pragma unroll
    for (int mi = 0; mi < 4; ++mi) {
        int crow0 = bm * 128 + wr * 64 + mi * 16 + hi * 4;
#pragma unroll
        for (int ni = 0; ni < 4; ++ni) {
            int ccol = bn * 128 + wc * 64 + ni * 16 + l15;
            float bv = bias[ccol];
            if constexpr (EPI == 0) {
                int which = ccol / 768;
                int rem   = ccol - which * 768;
                int hh = rem >> 6, hd = rem & 63;
                int bb = crow0 >> 10, nn0 = crow0 & 1023;
                size_t bh = (size_t)(bb * NH + hh);
                if (which == 2) {
                    uint2 pk;
                    pk.x = cvt_pk_bf16(acc[mi][ni][0] + bv, acc[mi][ni][1] + bv);
                    pk.y = cvt_pk_bf16(acc[mi][ni][2] + bv, acc[mi][ni][3] + bv);
                    *reinterpret_cast<uint2*>(&vt_out[(bh * HD + hd) * SEQ + nn0]) = pk;
                } else if (which == 0) {
#pragma unroll
                    for (int r = 0; r < 4; ++r)
                        q_out[(bh * SEQ + nn0 + r) * HD + hd] =
                            f2bu((acc[mi][ni][r] + bv) * 0.18033688f); // SCALE*log2e folded
                } else {
#pragma unroll
                    for (int r = 0; r < 4; ++r)
                        k_out[(bh * SEQ + nn0 + r) * HD + hd] = f2bu(acc[mi][ni][r] + bv);
                }
            } else {
#pragma unroll
                for (int r = 0; r < 4; ++r)
                    f_out[(size_t)(crow0 + r) * EMBED + ccol] = acc[mi][ni][r] + bv;
            }
        }
    }
}

// ---------------- flash attention v6: 8 waves x 16 q, in-register P transpose ----------------
// Swapped QK^T (S^T) + swapped PV (O^T). Lane (l15,hi): q = l15, k = kb*16 + 4*hi + r.
// P^T -> PA fragment via permlane32/16 swaps (no LDS roundtrip). LDS = K/V dbuf only (32 KB).
__global__ __launch_bounds__(512, 6)
void attn_k(const u16* __restrict__ Q, const u16* __restrict__ K,
            const u16* __restrict__ Vt, u16* __restrict__ AO)
{
    __shared__ __attribute__((aligned(16))) u16 kls[2][4096];   // K tile: 64 k x 64 d (swizzled)
    __shared__ __attribute__((aligned(16))) u16 vls[2][4096];   // V^T tile: 64 d x 64 k (swizzled)

    const int tid = threadIdx.x;
    const int w   = tid >> 6, lane = tid & 63;
    const int hi  = lane >> 4, l15 = lane & 15;
    const int f   = blockIdx.x;
    const int xcd = f & 7, i = f >> 3;
    const int bh  = xcd * 12 + (i % 12);
    const int q0w = (i / 12) * 128 + w * 16;   // this wave's 16 q-rows

    const u16* Qh = Q  + (size_t)bh * SEQ * HD;
    const u16* Kh = K  + (size_t)bh * SEQ * HD;
    const u16* Vh = Vt + (size_t)bh * HD * SEQ;

    // staging bases: wave w owns K chunk w and V chunk w (1 KB each)
    const int sp    = w * 1024 + lane * 16;
    const int srow  = sp >> 7;
    const int scolb = (sp & 127) ^ ((srow & 7) << 4);
    const u16* kbase = Kh + (size_t)srow * HD + (scolb >> 1);
    const u16* vbase = Vh + (size_t)srow * SEQ + (scolb >> 1);

    auto stage = [&](int buf, int t) {   // 2 gll per wave
        __builtin_amdgcn_global_load_lds(
            (const __attribute__((address_space(1))) void*)(kbase + (size_t)t * 64 * HD),
            (__attribute__((address_space(3))) void*)(&kls[buf][w * 512]), 16, 0, 0);
        __builtin_amdgcn_global_load_lds(
            (const __attribute__((address_space(1))) void*)(vbase + (size_t)t * 64),
            (__attribute__((address_space(3))) void*)(&vls[buf][w * 512]), 16, 0, 0);
    };

    stage(0, 0);

    short8 qf[2];   // B-operand: col = l15 = q, k(d) = dh*32 + hi*8 + j
#pragma unroll
    for (int dh = 0; dh < 2; ++dh)
        qf[dh] = *reinterpret_cast<const short8*>(
            Qh + (size_t)(q0w + l15) * HD + dh * 32 + hi * 8);

    f32x4 accO[4] = {};          // O^T: row d = db*16+4*hi+r, col q = l15
    float m = -1e30f, lp = 0.f;

    auto tile = [&](const u16* Kb, const u16* Vb) {
        // ---- QK^T from LDS: S^T[k][q] ----
        f32x4 st[4] = {};
        __builtin_amdgcn_s_setprio(1);
#pragma unroll
        for (int kb = 0; kb < 4; ++kb) {
            int R  = kb * 16 + l15;
            int sw = (R & 7) << 4;
            short8 kf0 = *reinterpret_cast<const short8*>(Kb + R * 64 + (((hi * 16) ^ sw) >> 1));
            short8 kf1 = *reinterpret_cast<const short8*>(Kb + R * 64 + (((64 + hi * 16) ^ sw) >> 1));
            st[kb] = MFMA(kf0, qf[0], st[kb]);
            st[kb] = MFMA(kf1, qf[1], st[kb]);
        }
        __builtin_amdgcn_s_setprio(0);

        // ---- online softmax (defer-max) ----
        float t0 = max3f(st[0][0], st[0][1], st[0][2]);
        float t1 = max3f(st[0][3], st[1][0], st[1][1]);
        float t2 = max3f(st[1][2], st[1][3], st[2][0]);
        float t3 = max3f(st[2][1], st[2][2], st[2][3]);
        float t4 = max3f(st[3][0], st[3][1], st[3][2]);
        float tm = fmaxf(max3f(t0, t1, t2), max3f(t3, t4, st[3][3]));
        tm = fmaxf(tm, __shfl_xor(tm, 16, 64));
        tm = fmaxf(tm, __shfl_xor(tm, 32, 64));
        if (!__all(tm <= m + 8.f)) {
            float mn = fmaxf(m, tm);
            float sc = exp2a(m - mn);
            m = mn;
            lp *= sc;
#pragma unroll
            for (int db = 0; db < 4; ++db)
#pragma unroll
                for (int r = 0; r < 4; ++r) accO[db][r] *= sc;
        }

        // ---- exp2 + pack: X[kb][c] = bf16 pair (e[2c], e[2c+1]) ----
        unsigned X[4][2];
#pragma unroll
        for (int kb = 0; kb < 4; ++kb) {
            float e0 = exp2a(st[kb][0] - m);
            float e1 = exp2a(st[kb][1] - m);
            float e2 = exp2a(st[kb][2] - m);
            float e3 = exp2a(st[kb][3] - m);
            lp += (e0 + e1) + (e2 + e3);
            X[kb][0] = cvt_pk_bf16(e0, e1);
            X[kb][1] = cvt_pk_bf16(e2, e3);
        }

        // ---- in-register transpose: P^T frags -> PA (B-operand) via permlane swaps ----
        // swap16(swap32(A,B)) quarters: A'=[A0,A2,B0,B2]=word(j01/j45-even-src), B'=[A1,A3,B1,B3]
        unsigned a0 = X[0][0], b0 = X[1][0];
        swap32(a0, b0); swap16(a0, b0);          // a0 = pa0.w0, b0 = pa0.w2
        unsigned a1 = X[0][1], b1 = X[1][1];
        swap32(a1, b1); swap16(a1, b1);          // a1 = pa0.w1, b1 = pa0.w3
        unsigned a2 = X[2][0], b2 = X[3][0];
        swap32(a2, b2); swap16(a2, b2);          // pa1.w0, pa1.w2
        unsigned a3 = X[2][1], b3 = X[3][1];
        swap32(a3, b3); swap16(a3, b3);          // pa1.w1, pa1.w3
        short8 pa0 = mk8(a0, a1, b0, b1);
        short8 pa1 = mk8(a2, a3, b2, b3);

        // ---- O^T += V^T * P from LDS ----
        __builtin_amdgcn_s_setprio(1);
#pragma unroll
        for (int db = 0; db < 4; ++db) {
            int R  = db * 16 + l15;
            int sw = (R & 7) << 4;
            short8 vf0 = *reinterpret_cast<const short8*>(Vb + R * 64 + (((hi * 16) ^ sw) >> 1));
            short8 vf1 = *reinterpret_cast<const short8*>(Vb + R * 64 + (((64 + hi * 16) ^ sw) >> 1));
            accO[db] = MFMA(vf0, pa0, accO[db]);
            accO[db] = MFMA(vf1, pa1, accO[db]);
        }
        __builtin_amdgcn_s_setprio(0);
    };

    for (int tt = 0; tt < 7; ++tt) {
        stage(1, 2 * tt + 1);
        WAITVM_BAR(2);
        tile(kls[0], vls[0]);
        BAR2();
        stage(0, 2 * tt + 2);
        WAITVM_BAR(2);
        tile(kls[1], vls[1]);
        BAR2();
    }
    stage(1, 15);
    WAITVM_BAR(2);
    tile(kls[0], vls[0]);
    BAR2();
    WAITVM_BAR(0);
    tile(kls[1], vls[1]);

    // final l reduction and store O^T -> AO rows
    lp += __shfl_xor(lp, 16, 64);
    lp += __shfl_xor(lp, 32, 64);
    float linv = 1.f / lp;
    const int bb = bh / NH, hh = bh - bb * NH;
    size_t rowb = ((size_t)bb * SEQ + q0w + l15) * EMBED + hh * HD;
#pragma unroll
    for (int db = 0; db < 4; ++db) {
        float o0 = accO[db][0] * linv, o1 = accO[db][1] * linv;
        float o2 = accO[db][2] * linv, o3 = accO[db][3] * linv;
        uint2 pkd;
        pkd.x = cvt_pk_bf16(o0, o1);
        pkd.y = cvt_pk_bf16(o2, o3);
        *reinterpret_cast<uint2*>(&AO[rowb + db * 16 + hi * 4]) = pkd;
    }
}

// ---------------- launch ----------------
extern "C" void kernel_launch(void* const* d_in, const int* in_sizes, int n_in,
                              void* d_out, int out_size, void* d_ws, size_t ws_size,
                              hipStream_t stream)
{
    const float* x      = (const float*)d_in[0];
    const float* qkv_w  = (const float*)d_in[1];
    const float* qkv_b  = (const float*)d_in[2];
    const float* proj_w = (const float*)d_in[3];
    const float* proj_b = (const float*)d_in[4];
    float* out = (float*)d_out;

    char* ws = (char*)d_ws;
    u16* xb  = (u16*)(ws);
    u16* wb  = (u16*)(ws + 12582912);
    u16* pw  = (u16*)(ws + 16121856);
    u16* qb  = (u16*)(ws + 17301504);
    u16* kb  = (u16*)(ws + 29884416);
    u16* vt  = (u16*)(ws + 42467328);
    u16* ao  = (u16*)(ws + 55050240);

    cvt_bf16_k<<<6144, 256, 0, stream>>>(x,      xb, BATCH * SEQ * EMBED);
    cvt_bf16_k<<<1728, 256, 0, stream>>>(qkv_w,  wb, 3 * EMBED * EMBED);
    cvt_bf16_k<<<576,  256, 0, stream>>>(proj_w, pw, EMBED * EMBED);

    gemm_bt_k<0><<<dim3(64, 18), 256, 0, stream>>>(xb, wb, qkv_b, qb, kb, vt, nullptr);
    attn_k<<<768, 512, 0, stream>>>(qb, kb, vt, ao);
    gemm_bt_k<1><<<dim3(64, 6), 256, 0, stream>>>(ao, pw, proj_b, nullptr, nullptr, nullptr, out);
}

// Round 8
// 103.838 us; speedup vs baseline: 2.6599x; 1.0311x over previous
//
#include <hip/hip_runtime.h>
#include <hip/hip_bf16.h>

typedef __attribute__((ext_vector_type(4))) float f32x4;
typedef __attribute__((ext_vector_type(8))) short short8;
typedef unsigned short u16;

#define MFMA(a, b, c) __builtin_amdgcn_mfma_f32_16x16x32_bf16((a), (b), (c), 0, 0, 0)

// counted-vmcnt barrier: my stage(t) landed, then all waves' landed.
#define WAITVM_BAR(N) do {                                          \
    asm volatile("s_waitcnt vmcnt(" #N ")" ::: "memory");           \
    __builtin_amdgcn_s_barrier();                                   \
    __builtin_amdgcn_sched_barrier(0);                              \
} while (0)
// read-completion barrier (no drain): protects buffer about to be re-staged.
#define BAR2() do {                                                 \
    __builtin_amdgcn_sched_barrier(0);                              \
    __builtin_amdgcn_s_barrier();                                   \
    __builtin_amdgcn_sched_barrier(0);                              \
} while (0)

static constexpr int EMBED = 768;
static constexpr int NH = 12;
static constexpr int HD = 64;
static constexpr int BATCH = 8;
static constexpr int SEQ = 1024;

__device__ __forceinline__ u16 f2bu(float f) {
    __hip_bfloat16 h = __float2bfloat16(f);
    u16 u; __builtin_memcpy(&u, &h, 2); return u;
}
__device__ __forceinline__ float exp2a(float x) {
    float r; asm("v_exp_f32 %0, %1" : "=v"(r) : "v"(x)); return r;
}
__device__ __forceinline__ unsigned cvt_pk_bf16(float lo, float hi) {
    unsigned r; asm("v_cvt_pk_bf16_f32 %0, %1, %2" : "=v"(r) : "v"(lo), "v"(hi)); return r;
}
__device__ __forceinline__ float max3f(float a, float b, float c) {
    return fmaxf(fmaxf(a, b), c);   // fuses to v_max3_f32
}
// a' = {a[0:31], b[0:31]}, b' = {a[32:63], b[32:63]}
__device__ __forceinline__ void swap32(unsigned& a, unsigned& b) {
    asm volatile("v_permlane32_swap_b32 %0, %1" : "+v"(a), "+v"(b));
}
// quarters: a' = [a0,b0,a2,b2], b' = [a1,b1,a3,b3]
__device__ __forceinline__ void swap16(unsigned& a, unsigned& b) {
    asm volatile("v_permlane16_swap_b32 %0, %1" : "+v"(a), "+v"(b));
}
__device__ __forceinline__ short8 mk8(unsigned w0, unsigned w1, unsigned w2, unsigned w3) {
    union { unsigned u[4]; short8 s; } c;
    c.u[0] = w0; c.u[1] = w1; c.u[2] = w2; c.u[3] = w3;
    return c.s;
}

// ---------------- fp32 -> bf16 convert (all three tensors, one launch) ----------------
__global__ void cvt_all_k(const float* __restrict__ x, const float* __restrict__ w1,
                          const float* __restrict__ w2,
                          u16* __restrict__ xb, u16* __restrict__ wb, u16* __restrict__ pw) {
    const int n1 = BATCH * SEQ * EMBED;        // 6291456
    const int n2 = 3 * EMBED * EMBED;          // 1769472
    const int n3 = EMBED * EMBED;              // 589824
    int i = (blockIdx.x * blockDim.x + threadIdx.x) * 4;
    const float* src; u16* dst;
    if (i < n1)            { src = x  + i;             dst = xb + i; }
    else if (i < n1 + n2)  { src = w1 + (i - n1);      dst = wb + (i - n1); }
    else if (i < n1+n2+n3) { src = w2 + (i - n1 - n2); dst = pw + (i - n1 - n2); }
    else return;
    float4 v = *reinterpret_cast<const float4*>(src);
    ushort4 o;
    o.x = f2bu(v.x); o.y = f2bu(v.y); o.z = f2bu(v.z); o.w = f2bu(v.w);
    *reinterpret_cast<ushort4*>(dst) = o;
}

// ---------------- bf16 B^T GEMM: C[M,N] = A[M,K] * Bw[N,K]^T + bias ----------------
// 128x128 tile, BK=64, 4 waves, double-buffered LDS, raw barriers + counted vmcnt(8).
template <int EPI>
__global__ __launch_bounds__(256)
void gemm_bt_k(const u16* __restrict__ A, const u16* __restrict__ Bw,
               const float* __restrict__ bias,
               u16* __restrict__ q_out, u16* __restrict__ k_out,
               u16* __restrict__ vt_out, float* __restrict__ f_out)
{
    __shared__ __attribute__((aligned(16))) char smem[65536]; // 2 x (A 16KB + B 16KB)
    const int tid  = threadIdx.x;
    const int wave = tid >> 6, lane = tid & 63;
    const int hi   = lane >> 4, l15 = lane & 15;
    const int wr   = wave >> 1, wc = wave & 1;
    const int bm   = blockIdx.x, bn = blockIdx.y;

    f32x4 acc[4][4] = {};

    const size_t arow0 = (size_t)bm * 128;
    const size_t brow0 = (size_t)bn * 128;

    auto stage = [&](int buf, int kt) {   // 8 gll per wave
        char* Ab = smem + buf * 32768;
        char* Bb = Ab + 16384;
#pragma unroll
        for (int c = 0; c < 4; ++c) {
            int ck   = c * 4 + wave;
            int p    = ck * 1024 + lane * 16;
            int row  = p >> 7;
            int pcol = (p & 127) ^ ((row & 7) << 4);
            const u16* srcA = A  + (arow0 + row) * EMBED + kt + (pcol >> 1);
            const u16* srcB = Bw + (brow0 + row) * EMBED + kt + (pcol >> 1);
            __builtin_amdgcn_global_load_lds((const __attribute__((address_space(1))) void*)srcA,
                                             (__attribute__((address_space(3))) void*)(Ab + ck * 1024), 16, 0, 0);
            __builtin_amdgcn_global_load_lds((const __attribute__((address_space(1))) void*)srcB,
                                             (__attribute__((address_space(3))) void*)(Bb + ck * 1024), 16, 0, 0);
        }
    };

    auto comp = [&](const char* Ab, const char* Bb) {
#pragma unroll
        for (int kk = 0; kk < 2; ++kk) {
            short8 af[4], bf[4];
#pragma unroll
            for (int mi = 0; mi < 4; ++mi) {
                int R  = wr * 64 + mi * 16 + l15;
                int Cb = kk * 64 + hi * 16;
                af[mi] = *reinterpret_cast<const short8*>(Ab + R * 128 + (Cb ^ ((R & 7) << 4)));
            }
#pragma unroll
            for (int ni = 0; ni < 4; ++ni) {
                int R  = wc * 64 + ni * 16 + l15;
                int Cb = kk * 64 + hi * 16;
                bf[ni] = *reinterpret_cast<const short8*>(Bb + R * 128 + (Cb ^ ((R & 7) << 4)));
            }
#pragma unroll
            for (int mi = 0; mi < 4; ++mi)
#pragma unroll
                for (int ni = 0; ni < 4; ++ni)
                    acc[mi][ni] = MFMA(af[mi], bf[ni], acc[mi][ni]);
        }
    };

    const char* A0 = smem;
    const char* B0 = smem + 16384;
    const char* A1 = smem + 32768;
    const char* B1 = smem + 49152;

    stage(0, 0);
#pragma unroll
    for (int tt = 0; tt < 5; ++tt) {
        stage(1, (2 * tt + 1) * 64);
        WAITVM_BAR(8);
        comp(A0, B0);
        BAR2();
        stage(0, (2 * tt + 2) * 64);
        WAITVM_BAR(8);
        comp(A1, B1);
        BAR2();
    }
    stage(1, 11 * 64);
    WAITVM_BAR(8);
    comp(A0, B0);
    BAR2();
    WAITVM_BAR(0);
    comp(A1, B1);

    // epilogue: C/D layout col = lane&15, row = 4*(lane>>4)+reg
#pragma unroll
    for (int mi = 0; mi < 4; ++mi) {
        int crow0 = bm * 128 + wr * 64 + mi * 16 + hi * 4;
#pragma unroll
        for (int ni = 0; ni < 4; ++ni) {
            int ccol = bn * 128 + wc * 64 + ni * 16 + l15;
            float bv = bias[ccol];
            if constexpr (EPI == 0) {
                int which = ccol / 768;
                int rem   = ccol - which * 768;
                int hh = rem >> 6, hd = rem & 63;
                int bb = crow0 >> 10, nn0 = crow0 & 1023;
                size_t bh = (size_t)(bb * NH + hh);
                if (which == 2) {
                    uint2 pk;
                    pk.x = cvt_pk_bf16(acc[mi][ni][0] + bv, acc[mi][ni][1] + bv);
                    pk.y = cvt_pk_bf16(acc[mi][ni][2] + bv, acc[mi][ni][3] + bv);
                    *reinterpret_cast<uint2*>(&vt_out[(bh * HD + hd) * SEQ + nn0]) = pk;
                } else if (which == 0) {
#pragma unroll
                    for (int r = 0; r < 4; ++r)
                        q_out[(bh * SEQ + nn0 + r) * HD + hd] =
                            f2bu((acc[mi][ni][r] + bv) * 0.18033688f); // SCALE*log2e folded
                } else {
#pragma unroll
                    for (int r = 0; r < 4; ++r)
                        k_out[(bh * SEQ + nn0 + r) * HD + hd] = f2bu(acc[mi][ni][r] + bv);
                }
            } else {
#pragma unroll
                for (int r = 0; r < 4; ++r)
                    f_out[(size_t)(crow0 + r) * EMBED + ccol] = acc[mi][ni][r] + bv;
            }
        }
    }
}

// ---------------- flash attention v7: 3-buffer rotation, ONE barrier per k-tile ----------------
// 8 waves x 16 q. Swapped QK^T (S^T) + swapped PV (O^T). Lane (l15,hi): q=l15, k=kb*16+4*hi+r.
// Per iter t: {vmcnt(2): S(t) landed; s_barrier; stage(t+2)->buf[(t+2)%3]; tile(buf[t%3])}.
// WAR safe: passing BAR(t) implies all waves completed tile(t-1) (precedes BAR(t) in prog order).
__global__ __launch_bounds__(512, 6)
void attn_k(const u16* __restrict__ Q, const u16* __restrict__ K,
            const u16* __restrict__ Vt, u16* __restrict__ AO)
{
    __shared__ __attribute__((aligned(16))) u16 kls[3][4096];   // K tiles: 64 k x 64 d (swizzled)
    __shared__ __attribute__((aligned(16))) u16 vls[3][4096];   // V^T tiles: 64 d x 64 k (swizzled)

    const int tid = threadIdx.x;
    const int w   = tid >> 6, lane = tid & 63;
    const int hi  = lane >> 4, l15 = lane & 15;
    const int f   = blockIdx.x;
    const int xcd = f & 7, i = f >> 3;
    const int bh  = xcd * 12 + (i % 12);
    const int q0w = (i / 12) * 128 + w * 16;   // this wave's 16 q-rows

    const u16* Qh = Q  + (size_t)bh * SEQ * HD;
    const u16* Kh = K  + (size_t)bh * SEQ * HD;
    const u16* Vh = Vt + (size_t)bh * HD * SEQ;

    // staging bases: wave w owns K chunk w and V chunk w (1 KB each)
    const int sp    = w * 1024 + lane * 16;
    const int srow  = sp >> 7;
    const int scolb = (sp & 127) ^ ((srow & 7) << 4);
    const u16* kbase = Kh + (size_t)srow * HD + (scolb >> 1);
    const u16* vbase = Vh + (size_t)srow * SEQ + (scolb >> 1);

    auto stage = [&](u16* kdst, u16* vdst, int t) {   // 2 gll per wave
        __builtin_amdgcn_global_load_lds(
            (const __attribute__((address_space(1))) void*)(kbase + (size_t)t * 64 * HD),
            (__attribute__((address_space(3))) void*)(kdst + w * 512), 16, 0, 0);
        __builtin_amdgcn_global_load_lds(
            (const __attribute__((address_space(1))) void*)(vbase + (size_t)t * 64),
            (__attribute__((address_space(3))) void*)(vdst + w * 512), 16, 0, 0);
    };

    // qf loads FIRST (oldest in vmcnt queue -> drained by the t=0 vmcnt(2))
    short8 qf[2];   // B-operand: col = l15 = q, k(d) = dh*32 + hi*8 + j
#pragma unroll
    for (int dh = 0; dh < 2; ++dh)
        qf[dh] = *reinterpret_cast<const short8*>(
            Qh + (size_t)(q0w + l15) * HD + dh * 32 + hi * 8);
    __builtin_amdgcn_sched_barrier(0);

    stage(kls[0], vls[0], 0);
    stage(kls[1], vls[1], 1);

    f32x4 accO[4] = {};          // O^T: row d = db*16+4*hi+r, col q = l15
    float m = -1e30f, lp = 0.f;

    auto tile = [&](const u16* Kb, const u16* Vb) {
        // ---- QK^T from LDS: S^T[k][q] ----
        f32x4 st[4] = {};
        __builtin_amdgcn_s_setprio(1);
#pragma unroll
        for (int kb = 0; kb < 4; ++kb) {
            int R  = kb * 16 + l15;
            int sw = (R & 7) << 4;
            short8 kf0 = *reinterpret_cast<const short8*>(Kb + R * 64 + (((hi * 16) ^ sw) >> 1));
            short8 kf1 = *reinterpret_cast<const short8*>(Kb + R * 64 + (((64 + hi * 16) ^ sw) >> 1));
            st[kb] = MFMA(kf0, qf[0], st[kb]);
            st[kb] = MFMA(kf1, qf[1], st[kb]);
        }
        __builtin_amdgcn_s_setprio(0);

        // ---- online softmax (defer-max) ----
        float t0 = max3f(st[0][0], st[0][1], st[0][2]);
        float t1 = max3f(st[0][3], st[1][0], st[1][1]);
        float t2 = max3f(st[1][2], st[1][3], st[2][0]);
        float t3 = max3f(st[2][1], st[2][2], st[2][3]);
        float t4 = max3f(st[3][0], st[3][1], st[3][2]);
        float tm = fmaxf(max3f(t0, t1, t2), max3f(t3, t4, st[3][3]));
        tm = fmaxf(tm, __shfl_xor(tm, 16, 64));
        tm = fmaxf(tm, __shfl_xor(tm, 32, 64));
        if (!__all(tm <= m + 8.f)) {
            float mn = fmaxf(m, tm);
            float sc = exp2a(m - mn);
            m = mn;
            lp *= sc;
#pragma unroll
            for (int db = 0; db < 4; ++db)
#pragma unroll
                for (int r = 0; r < 4; ++r) accO[db][r] *= sc;
        }

        // ---- exp2 + pack: X[kb][c] = bf16 pair (e[2c], e[2c+1]) ----
        unsigned X[4][2];
#pragma unroll
        for (int kb = 0; kb < 4; ++kb) {
            float e0 = exp2a(st[kb][0] - m);
            float e1 = exp2a(st[kb][1] - m);
            float e2 = exp2a(st[kb][2] - m);
            float e3 = exp2a(st[kb][3] - m);
            lp += (e0 + e1) + (e2 + e3);
            X[kb][0] = cvt_pk_bf16(e0, e1);
            X[kb][1] = cvt_pk_bf16(e2, e3);
        }

        // ---- in-register transpose: P^T frags -> PA (B-operand) via permlane swaps ----
        unsigned a0 = X[0][0], b0 = X[1][0];
        swap32(a0, b0); swap16(a0, b0);
        unsigned a1 = X[0][1], b1 = X[1][1];
        swap32(a1, b1); swap16(a1, b1);
        unsigned a2 = X[2][0], b2 = X[3][0];
        swap32(a2, b2); swap16(a2, b2);
        unsigned a3 = X[2][1], b3 = X[3][1];
        swap32(a3, b3); swap16(a3, b3);
        short8 pa0 = mk8(a0, a1, b0, b1);
        short8 pa1 = mk8(a2, a3, b2, b3);

        // ---- O^T += V^T * P from LDS ----
        __builtin_amdgcn_s_setprio(1);
#pragma unroll
        for (int db = 0; db < 4; ++db) {
            int R  = db * 16 + l15;
            int sw = (R & 7) << 4;
            short8 vf0 = *reinterpret_cast<const short8*>(Vb + R * 64 + (((hi * 16) ^ sw) >> 1));
            short8 vf1 = *reinterpret_cast<const short8*>(Vb + R * 64 + (((64 + hi * 16) ^ sw) >> 1));
            accO[db] = MFMA(vf0, pa0, accO[db]);
            accO[db] = MFMA(vf1, pa1, accO[db]);
        }
        __builtin_amdgcn_s_setprio(0);
    };

    // one iteration: vmcnt(2) [S(t) landed], barrier, prefetch t+2, compute t
    auto one = [&](const u16* Kc, const u16* Vc, u16* Ks, u16* Vs, int tn, bool ds) {
        asm volatile("s_waitcnt vmcnt(2)" ::: "memory");
        __builtin_amdgcn_s_barrier();
        __builtin_amdgcn_sched_barrier(0);
        if (ds) stage(Ks, Vs, tn);
        tile(Kc, Vc);
        __builtin_amdgcn_sched_barrier(0);
    };

    for (int g = 0; g < 5; ++g) {           // t = 3g, 3g+1, 3g+2  (0..14)
        one(kls[0], vls[0], kls[2], vls[2], 3 * g + 2, true);
        one(kls[1], vls[1], kls[0], vls[0], 3 * g + 3, 3 * g + 3 <= 15);
        one(kls[2], vls[2], kls[1], vls[1], 3 * g + 4, 3 * g + 4 <= 15);
    }
    // t = 15 (15 % 3 == 0)
    asm volatile("s_waitcnt vmcnt(0)" ::: "memory");
    __builtin_amdgcn_s_barrier();
    __builtin_amdgcn_sched_barrier(0);
    tile(kls[0], vls[0]);

    // final l reduction and store O^T -> AO rows
    lp += __shfl_xor(lp, 16, 64);
    lp += __shfl_xor(lp, 32, 64);
    float linv = 1.f / lp;
    const int bb = bh / NH, hh = bh - bb * NH;
    size_t rowb = ((size_t)bb * SEQ + q0w + l15) * EMBED + hh * HD;
#pragma unroll
    for (int db = 0; db < 4; ++db) {
        float o0 = accO[db][0] * linv, o1 = accO[db][1] * linv;
        float o2 = accO[db][2] * linv, o3 = accO[db][3] * linv;
        uint2 pkd;
        pkd.x = cvt_pk_bf16(o0, o1);
        pkd.y = cvt_pk_bf16(o2, o3);
        *reinterpret_cast<uint2*>(&AO[rowb + db * 16 + hi * 4]) = pkd;
    }
}

// ---------------- launch ----------------
extern "C" void kernel_launch(void* const* d_in, const int* in_sizes, int n_in,
                              void* d_out, int out_size, void* d_ws, size_t ws_size,
                              hipStream_t stream)
{
    const float* x      = (const float*)d_in[0];
    const float* qkv_w  = (const float*)d_in[1];
    const float* qkv_b  = (const float*)d_in[2];
    const float* proj_w = (const float*)d_in[3];
    const float* proj_b = (const float*)d_in[4];
    float* out = (float*)d_out;

    char* ws = (char*)d_ws;
    u16* xb  = (u16*)(ws);
    u16* wb  = (u16*)(ws + 12582912);
    u16* pw  = (u16*)(ws + 16121856);
    u16* qb  = (u16*)(ws + 17301504);
    u16* kb  = (u16*)(ws + 29884416);
    u16* vt  = (u16*)(ws + 42467328);
    u16* ao  = (u16*)(ws + 55050240);

    cvt_all_k<<<8448, 256, 0, stream>>>(x, qkv_w, proj_w, xb, wb, pw);

    gemm_bt_k<0><<<dim3(64, 18), 256, 0, stream>>>(xb, wb, qkv_b, qb, kb, vt, nullptr);
    attn_k<<<768, 512, 0, stream>>>(qb, kb, vt, ao);
    gemm_bt_k<1><<<dim3(64, 6), 256, 0, stream>>>(ao, pw, proj_b, nullptr, nullptr, nullptr, out);
}

// Round 9
// 103.314 us; speedup vs baseline: 2.6734x; 1.0051x over previous
//
#include <hip/hip_runtime.h>
#include <hip/hip_bf16.h>

typedef __attribute__((ext_vector_type(4))) float f32x4;
typedef __attribute__((ext_vector_type(8))) short short8;
typedef unsigned short u16;

#define MFMA(a, b, c) __builtin_amdgcn_mfma_f32_16x16x32_bf16((a), (b), (c), 0, 0, 0)

#define WAITVM_BAR(N) do {                                          \
    asm volatile("s_waitcnt vmcnt(" #N ")" ::: "memory");           \
    __builtin_amdgcn_s_barrier();                                   \
    __builtin_amdgcn_sched_barrier(0);                              \
} while (0)
#define BAR2() do {                                                 \
    __builtin_amdgcn_sched_barrier(0);                              \
    __builtin_amdgcn_s_barrier();                                   \
    __builtin_amdgcn_sched_barrier(0);                              \
} while (0)

static constexpr int EMBED = 768;
static constexpr int NH = 12;
static constexpr int HD = 64;
static constexpr int BATCH = 8;
static constexpr int SEQ = 1024;

__device__ __forceinline__ u16 f2bu(float f) {
    __hip_bfloat16 h = __float2bfloat16(f);
    u16 u; __builtin_memcpy(&u, &h, 2); return u;
}
__device__ __forceinline__ float exp2a(float x) {
    float r; asm("v_exp_f32 %0, %1" : "=v"(r) : "v"(x)); return r;
}
__device__ __forceinline__ unsigned cvt_pk_bf16(float lo, float hi) {
    unsigned r; asm("v_cvt_pk_bf16_f32 %0, %1, %2" : "=v"(r) : "v"(lo), "v"(hi)); return r;
}
__device__ __forceinline__ float max3f(float a, float b, float c) {
    return fmaxf(fmaxf(a, b), c);
}
__device__ __forceinline__ void swap32(unsigned& a, unsigned& b) {
    asm volatile("v_permlane32_swap_b32 %0, %1" : "+v"(a), "+v"(b));
}
__device__ __forceinline__ void swap16(unsigned& a, unsigned& b) {
    asm volatile("v_permlane16_swap_b32 %0, %1" : "+v"(a), "+v"(b));
}
__device__ __forceinline__ short8 mk8(unsigned w0, unsigned w1, unsigned w2, unsigned w3) {
    union { unsigned u[4]; short8 s; } c;
    c.u[0] = w0; c.u[1] = w1; c.u[2] = w2; c.u[3] = w3;
    return c.s;
}

// ---------------- fp32 -> bf16 convert (all three tensors, one launch) ----------------
__global__ void cvt_all_k(const float* __restrict__ x, const float* __restrict__ w1,
                          const float* __restrict__ w2,
                          u16* __restrict__ xb, u16* __restrict__ wb, u16* __restrict__ pw) {
    const int n1 = BATCH * SEQ * EMBED;
    const int n2 = 3 * EMBED * EMBED;
    const int n3 = EMBED * EMBED;
    int i = (blockIdx.x * blockDim.x + threadIdx.x) * 4;
    const float* src; u16* dst;
    if (i < n1)            { src = x  + i;             dst = xb + i; }
    else if (i < n1 + n2)  { src = w1 + (i - n1);      dst = wb + (i - n1); }
    else if (i < n1+n2+n3) { src = w2 + (i - n1 - n2); dst = pw + (i - n1 - n2); }
    else return;
    float4 v = *reinterpret_cast<const float4*>(src);
    ushort4 o;
    o.x = f2bu(v.x); o.y = f2bu(v.y); o.z = f2bu(v.z); o.w = f2bu(v.w);
    *reinterpret_cast<ushort4*>(dst) = o;
}

// ---------------- bf16 B^T GEMM: C[M,N] = A[M,K] * Bw[N,K]^T + bias ----------------
template <int EPI>
__global__ __launch_bounds__(256)
void gemm_bt_k(const u16* __restrict__ A, const u16* __restrict__ Bw,
               const float* __restrict__ bias,
               u16* __restrict__ q_out, u16* __restrict__ k_out,
               u16* __restrict__ vt_out, float* __restrict__ f_out)
{
    __shared__ __attribute__((aligned(16))) char smem[65536];
    const int tid  = threadIdx.x;
    const int wave = tid >> 6, lane = tid & 63;
    const int hi   = lane >> 4, l15 = lane & 15;
    const int wr   = wave >> 1, wc = wave & 1;
    const int bm   = blockIdx.x, bn = blockIdx.y;

    f32x4 acc[4][4] = {};

    const size_t arow0 = (size_t)bm * 128;
    const size_t brow0 = (size_t)bn * 128;

    auto stage = [&](int buf, int kt) {
        char* Ab = smem + buf * 32768;
        char* Bb = Ab + 16384;
#pragma unroll
        for (int c = 0; c < 4; ++c) {
            int ck   = c * 4 + wave;
            int p    = ck * 1024 + lane * 16;
            int row  = p >> 7;
            int pcol = (p & 127) ^ ((row & 7) << 4);
            const u16* srcA = A  + (arow0 + row) * EMBED + kt + (pcol >> 1);
            const u16* srcB = Bw + (brow0 + row) * EMBED + kt + (pcol >> 1);
            __builtin_amdgcn_global_load_lds((const __attribute__((address_space(1))) void*)srcA,
                                             (__attribute__((address_space(3))) void*)(Ab + ck * 1024), 16, 0, 0);
            __builtin_amdgcn_global_load_lds((const __attribute__((address_space(1))) void*)srcB,
                                             (__attribute__((address_space(3))) void*)(Bb + ck * 1024), 16, 0, 0);
        }
    };

    auto comp = [&](const char* Ab, const char* Bb) {
#pragma unroll
        for (int kk = 0; kk < 2; ++kk) {
            short8 af[4], bf[4];
#pragma unroll
            for (int mi = 0; mi < 4; ++mi) {
                int R  = wr * 64 + mi * 16 + l15;
                int Cb = kk * 64 + hi * 16;
                af[mi] = *reinterpret_cast<const short8*>(Ab + R * 128 + (Cb ^ ((R & 7) << 4)));
            }
#pragma unroll
            for (int ni = 0; ni < 4; ++ni) {
                int R  = wc * 64 + ni * 16 + l15;
                int Cb = kk * 64 + hi * 16;
                bf[ni] = *reinterpret_cast<const short8*>(Bb + R * 128 + (Cb ^ ((R & 7) << 4)));
            }
#pragma unroll
            for (int mi = 0; mi < 4; ++mi)
#pragma unroll
                for (int ni = 0; ni < 4; ++ni)
                    acc[mi][ni] = MFMA(af[mi], bf[ni], acc[mi][ni]);
        }
    };

    const char* A0 = smem;
    const char* B0 = smem + 16384;
    const char* A1 = smem + 32768;
    const char* B1 = smem + 49152;

    stage(0, 0);
#pragma unroll
    for (int tt = 0; tt < 5; ++tt) {
        stage(1, (2 * tt + 1) * 64);
        WAITVM_BAR(8);
        comp(A0, B0);
        BAR2();
        stage(0, (2 * tt + 2) * 64);
        WAITVM_BAR(8);
        comp(A1, B1);
        BAR2();
    }
    stage(1, 11 * 64);
    WAITVM_BAR(8);
    comp(A0, B0);
    BAR2();
    WAITVM_BAR(0);
    comp(A1, B1);

#pragma unroll
    for (int mi = 0; mi < 4; ++mi) {
        int crow0 = bm * 128 + wr * 64 + mi * 16 + hi * 4;
#pragma unroll
        for (int ni = 0; ni < 4; ++ni) {
            int ccol = bn * 128 + wc * 64 + ni * 16 + l15;
            float bv = bias[ccol];
            if constexpr (EPI == 0) {
                int which = ccol / 768;
                int rem   = ccol - which * 768;
                int hh = rem >> 6, hd = rem & 63;
                int bb = crow0 >> 10, nn0 = crow0 & 1023;
                size_t bh = (size_t)(bb * NH + hh);
                if (which == 2) {
                    uint2 pk;
                    pk.x = cvt_pk_bf16(acc[mi][ni][0] + bv, acc[mi][ni][1] + bv);
                    pk.y = cvt_pk_bf16(acc[mi][ni][2] + bv, acc[mi][ni][3] + bv);
                    *reinterpret_cast<uint2*>(&vt_out[(bh * HD + hd) * SEQ + nn0]) = pk;
                } else if (which == 0) {
#pragma unroll
                    for (int r = 0; r < 4; ++r)
                        q_out[(bh * SEQ + nn0 + r) * HD + hd] =
                            f2bu((acc[mi][ni][r] + bv) * 0.18033688f);
                } else {
#pragma unroll
                    for (int r = 0; r < 4; ++r)
                        k_out[(bh * SEQ + nn0 + r) * HD + hd] = f2bu(acc[mi][ni][r] + bv);
                }
            } else {
#pragma unroll
                for (int r = 0; r < 4; ++r)
                    f_out[(size_t)(crow0 + r) * EMBED + ccol] = acc[mi][ni][r] + bv;
            }
        }
    }
}

// ---------------- flash attention v8: 4 waves x 32 q, speculative softmax ----------------
// Halves per-CU LDS-read traffic vs v7 (same K/V frags feed 2 q-frags). Tiles >=1 compute
// exp2 with the PREVIOUS running max immediately (no wait on max-reduce); rare post-PV
// fixup rescales accO/lp exactly. Lane (l15,hi): q = q0w + qh*16 + l15, k = kb*16+4*hi+r.
__global__ __launch_bounds__(256, 3)
void attn_k(const u16* __restrict__ Q, const u16* __restrict__ K,
            const u16* __restrict__ Vt, u16* __restrict__ AO)
{
    __shared__ __attribute__((aligned(16))) u16 kv[3][8192];  // [0:4095]=K tile, [4096:8191]=V^T tile

    const int tid = threadIdx.x;
    const int w   = tid >> 6, lane = tid & 63;
    const int hi  = lane >> 4, l15 = lane & 15;
    const int f   = blockIdx.x;
    const int xcd = f & 7, i = f >> 3;
    const int bh  = xcd * 12 + (i % 12);
    const int q0w = (i / 12) * 128 + w * 32;    // this wave's 32 q-rows

    const u16* Qh = Q  + (size_t)bh * SEQ * HD;
    const u16* Kh = K  + (size_t)bh * SEQ * HD;
    const u16* Vh = Vt + (size_t)bh * HD * SEQ;

    // qf loads FIRST (oldest in vmcnt queue -> drained by first vmcnt(4))
    short8 qf[2][2];
#pragma unroll
    for (int qh = 0; qh < 2; ++qh)
#pragma unroll
        for (int dh = 0; dh < 2; ++dh)
            qf[qh][dh] = *reinterpret_cast<const short8*>(
                Qh + (size_t)(q0w + qh * 16 + l15) * HD + dh * 32 + hi * 8);
    __builtin_amdgcn_sched_barrier(0);

    // staging: 16 chunks of 1KB (8 K + 8 V), 4 per wave; branch resolves at compile time per c
    const u16* sptr[4]; int doff[4]; int sadv[4];
#pragma unroll
    for (int c = 0; c < 4; ++c) {
        int ch = c * 4 + w;
        int mc = ch & 7;
        int p  = mc * 1024 + lane * 16;
        int row = p >> 7;
        int colb = (p & 127) ^ ((row & 7) << 4);
        if (ch < 8) { sptr[c] = Kh + (size_t)row * HD + (colb >> 1); sadv[c] = 64 * HD; doff[c] = mc * 512; }
        else        { sptr[c] = Vh + (size_t)row * SEQ + (colb >> 1); sadv[c] = 64;     doff[c] = 4096 + mc * 512; }
    }
    auto stage = [&](int buf, int t) {   // 4 gll per wave
#pragma unroll
        for (int c = 0; c < 4; ++c)
            __builtin_amdgcn_global_load_lds(
                (const __attribute__((address_space(1))) void*)(sptr[c] + (size_t)t * sadv[c]),
                (__attribute__((address_space(3))) void*)(&kv[buf][doff[c]]), 16, 0, 0);
    };

    stage(0, 0);
    stage(1, 1);

    f32x4 accO0[4] = {}, accO1[4] = {};   // O^T per qh: row d = db*16+4*hi+r, col q = l15
    float m0 = 0.f, m1 = 0.f, lp0 = 0.f, lp1 = 0.f;

    auto tile = [&](const u16* Kb, const u16* Vb, bool first) {
        f32x4 st0[4] = {}, st1[4] = {};
        __builtin_amdgcn_s_setprio(1);
#pragma unroll
        for (int kb = 0; kb < 4; ++kb) {
            int R  = kb * 16 + l15;
            int sw = (R & 7) << 4;
            short8 kf0 = *reinterpret_cast<const short8*>(Kb + R * 64 + (((hi * 16) ^ sw) >> 1));
            short8 kf1 = *reinterpret_cast<const short8*>(Kb + R * 64 + (((64 + hi * 16) ^ sw) >> 1));
            st0[kb] = MFMA(kf0, qf[0][0], st0[kb]);
            st0[kb] = MFMA(kf1, qf[0][1], st0[kb]);
            st1[kb] = MFMA(kf0, qf[1][0], st1[kb]);
            st1[kb] = MFMA(kf1, qf[1][1], st1[kb]);
        }
        __builtin_amdgcn_s_setprio(0);

        // wave-max per qh (off critical path when !first; feeds init when first)
        float a0 = max3f(st0[0][0], st0[0][1], st0[0][2]);
        float a1 = max3f(st0[0][3], st0[1][0], st0[1][1]);
        float a2 = max3f(st0[1][2], st0[1][3], st0[2][0]);
        float a3 = max3f(st0[2][1], st0[2][2], st0[2][3]);
        float a4 = max3f(st0[3][0], st0[3][1], st0[3][2]);
        float tm0 = fmaxf(max3f(a0, a1, a2), max3f(a3, a4, st0[3][3]));
        float b0 = max3f(st1[0][0], st1[0][1], st1[0][2]);
        float b1 = max3f(st1[0][3], st1[1][0], st1[1][1]);
        float b2 = max3f(st1[1][2], st1[1][3], st1[2][0]);
        float b3 = max3f(st1[2][1], st1[2][2], st1[2][3]);
        float b4 = max3f(st1[3][0], st1[3][1], st1[3][2]);
        float tm1 = fmaxf(max3f(b0, b1, b2), max3f(b3, b4, st1[3][3]));
        tm0 = fmaxf(tm0, __shfl_xor(tm0, 16, 64));
        tm0 = fmaxf(tm0, __shfl_xor(tm0, 32, 64));
        tm1 = fmaxf(tm1, __shfl_xor(tm1, 16, 64));
        tm1 = fmaxf(tm1, __shfl_xor(tm1, 32, 64));
        if (first) { m0 = tm0; m1 = tm1; }

        // speculative exp2 (uses current m; exact when first)
        unsigned X0[4][2], X1[4][2];
#pragma unroll
        for (int kb = 0; kb < 4; ++kb) {
            float e0 = exp2a(st0[kb][0] - m0);
            float e1 = exp2a(st0[kb][1] - m0);
            float e2 = exp2a(st0[kb][2] - m0);
            float e3 = exp2a(st0[kb][3] - m0);
            lp0 += (e0 + e1) + (e2 + e3);
            X0[kb][0] = cvt_pk_bf16(e0, e1);
            X0[kb][1] = cvt_pk_bf16(e2, e3);
            float g0 = exp2a(st1[kb][0] - m1);
            float g1 = exp2a(st1[kb][1] - m1);
            float g2 = exp2a(st1[kb][2] - m1);
            float g3 = exp2a(st1[kb][3] - m1);
            lp1 += (g0 + g1) + (g2 + g3);
            X1[kb][0] = cvt_pk_bf16(g0, g1);
            X1[kb][1] = cvt_pk_bf16(g2, g3);
        }

        // in-register transpose per qh: P^T -> PA (B-operand) via permlane swaps
        unsigned c0 = X0[0][0], d0 = X0[1][0];
        swap32(c0, d0); swap16(c0, d0);
        unsigned c1 = X0[0][1], d1 = X0[1][1];
        swap32(c1, d1); swap16(c1, d1);
        unsigned c2 = X0[2][0], d2 = X0[3][0];
        swap32(c2, d2); swap16(c2, d2);
        unsigned c3 = X0[2][1], d3 = X0[3][1];
        swap32(c3, d3); swap16(c3, d3);
        short8 pa00 = mk8(c0, c1, d0, d1);
        short8 pa01 = mk8(c2, c3, d2, d3);
        unsigned e0 = X1[0][0], f0 = X1[1][0];
        swap32(e0, f0); swap16(e0, f0);
        unsigned e1 = X1[0][1], f1 = X1[1][1];
        swap32(e1, f1); swap16(e1, f1);
        unsigned e2 = X1[2][0], f2 = X1[3][0];
        swap32(e2, f2); swap16(e2, f2);
        unsigned e3 = X1[2][1], f3 = X1[3][1];
        swap32(e3, f3); swap16(e3, f3);
        short8 pa10 = mk8(e0, e1, f0, f1);
        short8 pa11 = mk8(e2, e3, f2, f3);

        // O^T += V^T * P (V-frags shared across both qh)
        __builtin_amdgcn_s_setprio(1);
#pragma unroll
        for (int db = 0; db < 4; ++db) {
            int R  = db * 16 + l15;
            int sw = (R & 7) << 4;
            short8 vf0 = *reinterpret_cast<const short8*>(Vb + R * 64 + (((hi * 16) ^ sw) >> 1));
            short8 vf1 = *reinterpret_cast<const short8*>(Vb + R * 64 + (((64 + hi * 16) ^ sw) >> 1));
            accO0[db] = MFMA(vf0, pa00, accO0[db]);
            accO0[db] = MFMA(vf1, pa01, accO0[db]);
            accO1[db] = MFMA(vf0, pa10, accO1[db]);
            accO1[db] = MFMA(vf1, pa11, accO1[db]);
        }
        __builtin_amdgcn_s_setprio(0);

        // rare exact fixup: rescale EVERYTHING (incl. this tile) to the new max
        if (!first && !__all((tm0 <= m0 + 8.f) && (tm1 <= m1 + 8.f))) {
            float mn0 = fmaxf(m0, tm0), mn1 = fmaxf(m1, tm1);
            float s0 = exp2a(m0 - mn0), s1 = exp2a(m1 - mn1);
            m0 = mn0; m1 = mn1;
            lp0 *= s0; lp1 *= s1;
#pragma unroll
            for (int db = 0; db < 4; ++db)
#pragma unroll
                for (int r = 0; r < 4; ++r) { accO0[db][r] *= s0; accO1[db][r] *= s1; }
        }
    };

    // one iteration: vmcnt(4) [S(t) landed], barrier, prefetch t+2, compute t
    auto one = [&](int bc, int bs, int tn, bool ds, bool first) {
        asm volatile("s_waitcnt vmcnt(4)" ::: "memory");
        __builtin_amdgcn_s_barrier();
        __builtin_amdgcn_sched_barrier(0);
        if (ds) stage(bs, tn);
        tile(&kv[bc][0], &kv[bc][4096], first);
        __builtin_amdgcn_sched_barrier(0);
    };

    one(0, 2, 2, true, true);
    one(1, 0, 3, true, false);
    one(2, 1, 4, true, false);
    for (int g = 1; g < 5; ++g) {
        one(0, 2, 3 * g + 2, true, false);
        one(1, 0, 3 * g + 3, 3 * g + 3 <= 15, false);
        one(2, 1, 3 * g + 4, 3 * g + 4 <= 15, false);
    }
    // t = 15 (buf 0)
    asm volatile("s_waitcnt vmcnt(0)" ::: "memory");
    __builtin_amdgcn_s_barrier();
    __builtin_amdgcn_sched_barrier(0);
    tile(&kv[0][0], &kv[0][4096], false);

    // final l reduction and O^T store
    lp0 += __shfl_xor(lp0, 16, 64);
    lp0 += __shfl_xor(lp0, 32, 64);
    lp1 += __shfl_xor(lp1, 16, 64);
    lp1 += __shfl_xor(lp1, 32, 64);
    float linv0 = 1.f / lp0, linv1 = 1.f / lp1;
    const int bb = bh / NH, hh = bh - bb * NH;
    size_t rowb0 = ((size_t)bb * SEQ + q0w + l15) * EMBED + hh * HD;
    size_t rowb1 = rowb0 + (size_t)16 * EMBED;
#pragma unroll
    for (int db = 0; db < 4; ++db) {
        uint2 pk0, pk1;
        pk0.x = cvt_pk_bf16(accO0[db][0] * linv0, accO0[db][1] * linv0);
        pk0.y = cvt_pk_bf16(accO0[db][2] * linv0, accO0[db][3] * linv0);
        pk1.x = cvt_pk_bf16(accO1[db][0] * linv1, accO1[db][1] * linv1);
        pk1.y = cvt_pk_bf16(accO1[db][2] * linv1, accO1[db][3] * linv1);
        *reinterpret_cast<uint2*>(&AO[rowb0 + db * 16 + hi * 4]) = pk0;
        *reinterpret_cast<uint2*>(&AO[rowb1 + db * 16 + hi * 4]) = pk1;
    }
}

// ---------------- launch ----------------
extern "C" void kernel_launch(void* const* d_in, const int* in_sizes, int n_in,
                              void* d_out, int out_size, void* d_ws, size_t ws_size,
                              hipStream_t stream)
{
    const float* x      = (const float*)d_in[0];
    const float* qkv_w  = (const float*)d_in[1];
    const float* qkv_b  = (const float*)d_in[2];
    const float* proj_w = (const float*)d_in[3];
    const float* proj_b = (const float*)d_in[4];
    float* out = (float*)d_out;

    char* ws = (char*)d_ws;
    u16* xb  = (u16*)(ws);
    u16* wb  = (u16*)(ws + 12582912);
    u16* pw  = (u16*)(ws + 16121856);
    u16* qb  = (u16*)(ws + 17301504);
    u16* kb  = (u16*)(ws + 29884416);
    u16* vt  = (u16*)(ws + 42467328);
    u16* ao  = (u16*)(ws + 55050240);

    cvt_all_k<<<8448, 256, 0, stream>>>(x, qkv_w, proj_w, xb, wb, pw);

    gemm_bt_k<0><<<dim3(64, 18), 256, 0, stream>>>(xb, wb, qkv_b, qb, kb, vt, nullptr);
    attn_k<<<768, 256, 0, stream>>>(qb, kb, vt, ao);
    gemm_bt_k<1><<<dim3(64, 6), 256, 0, stream>>>(ao, pw, proj_b, nullptr, nullptr, nullptr, out);
}